// Round 5
// baseline (859.629 us; speedup 1.0000x reference)
//
#include <hip/hip_runtime.h>
#include <math.h>

#define N_NODES 100000
#define N_EDGES 1600000
#define N_GRAPHS 256
#define BN_EPS 1e-5f

// ---------------- CSR build ----------------
__global__ void hist_kernel(const int* __restrict__ ei, int* __restrict__ deg) {
    int e = blockIdx.x * blockDim.x + threadIdx.x;
    if (e < N_EDGES) atomicAdd(&deg[ei[N_EDGES + e]], 1);
}

__global__ void scan1_kernel(const int* __restrict__ deg, int* __restrict__ rowptr,
                             int* __restrict__ bsum) {
    __shared__ int s[256];
    int tid = threadIdx.x;
    int i = blockIdx.x * 256 + tid;
    int v = (i < N_NODES) ? deg[i] : 0;
    s[tid] = v; __syncthreads();
    for (int off = 1; off < 256; off <<= 1) {
        int t = (tid >= off) ? s[tid - off] : 0; __syncthreads();
        s[tid] += t; __syncthreads();
    }
    if (i < N_NODES) rowptr[i] = s[tid] - v;   // exclusive
    if (tid == 255) bsum[blockIdx.x] = s[255];
}

__global__ void scan2_kernel(int* bsum, int nb) {
    __shared__ int s[512];
    int tid = threadIdx.x;
    int v = (tid < nb) ? bsum[tid] : 0;
    s[tid] = v; __syncthreads();
    for (int off = 1; off < 512; off <<= 1) {
        int t = (tid >= off) ? s[tid - off] : 0; __syncthreads();
        s[tid] += t; __syncthreads();
    }
    if (tid < nb) bsum[tid] = s[tid] - v;      // exclusive
}

__global__ void scan3_kernel(int* __restrict__ rowptr, const int* __restrict__ bsum) {
    int i = blockIdx.x * 256 + threadIdx.x;
    if (i < N_NODES) rowptr[i] += bsum[blockIdx.x];
    if (i == 0) rowptr[N_NODES] = N_EDGES;
}

__global__ void scatter_kernel(const int* __restrict__ ei, const float* __restrict__ ew,
                               const int* __restrict__ rowptr, int* __restrict__ cnt,
                               int* __restrict__ ssrc, float* __restrict__ swt) {
    int e = blockIdx.x * blockDim.x + threadIdx.x;
    if (e >= N_EDGES) return;
    int dst = ei[N_EDGES + e];
    int pos = rowptr[dst] + atomicAdd(&cnt[dst], 1);
    ssrc[pos] = ei[e];
    swt[pos] = ew[e];
}

// ---------------- misc precompute ----------------
__global__ void bnprep_kernel(const float* __restrict__ v1, const float* __restrict__ v2,
                              const float* __restrict__ v3, float* __restrict__ rs) {
    int t = threadIdx.x;
    if (t < 128) rs[t] = 1.0f / sqrtf(v1[t] + BN_EPS);
    if (t < 64)  rs[128 + t] = 1.0f / sqrtf(v2[t] + BN_EPS);
    if (t < 32)  rs[192 + t] = 1.0f / sqrtf(v3[t] + BN_EPS);
}

__global__ void starts_kernel(const int* __restrict__ batch, int* __restrict__ starts) {
    int i = blockIdx.x * 256 + threadIdx.x;
    if (i >= N_NODES) return;
    int b = batch[i];
    int bp = (i == 0) ? -1 : batch[i - 1];
    for (int g = bp + 1; g <= b; ++g) starts[g] = i;
    if (i == N_NODES - 1)
        for (int g = b + 1; g <= N_GRAPHS; ++g) starts[g] = N_NODES;
}

// pad x [N,29] -> xp [N,32] (zeros in 29..31)
__global__ __launch_bounds__(256) void pad_x_kernel(const float* __restrict__ x,
                                                    float* __restrict__ xp) {
    int i = blockIdx.x * 256 + threadIdx.x;
    if (i >= N_NODES * 32) return;
    int n = i >> 5, c = i & 31;
    xp[i] = (c < 29) ? x[n * 29 + c] : 0.f;
}

// ---------------- layer-1 gather on padded x: agg[N,32] ----------------
__global__ __launch_bounds__(256) void agg_x_kernel(const float* __restrict__ xp,
        const int* __restrict__ rowptr, const int* __restrict__ ssrc,
        const float* __restrict__ swt, float* __restrict__ agg) {
    int tid = threadIdx.x;
    int node = blockIdx.x * 32 + (tid >> 3);
    int c = (tid & 7) * 4;
    int e0 = rowptr[node], e1 = rowptr[node + 1];
    float4 acc = {0.f, 0.f, 0.f, 0.f};
    int e = e0;
    // align e to 4 (order-preserving)
    for (; e < e1 && (e & 3); ++e) {
        int s0 = ssrc[e]; float w0 = swt[e];
        float4 y0 = *(const float4*)&xp[(size_t)s0 * 32 + c];
        acc.x = fmaf(w0, y0.x, acc.x); acc.y = fmaf(w0, y0.y, acc.y);
        acc.z = fmaf(w0, y0.z, acc.z); acc.w = fmaf(w0, y0.w, acc.w);
    }
    for (; e + 4 <= e1; e += 4) {
        int4   s4 = *(const int4*)&ssrc[e];
        float4 w4 = *(const float4*)&swt[e];
        float4 y0 = *(const float4*)&xp[(size_t)s4.x * 32 + c];
        float4 y1 = *(const float4*)&xp[(size_t)s4.y * 32 + c];
        float4 y2 = *(const float4*)&xp[(size_t)s4.z * 32 + c];
        float4 y3 = *(const float4*)&xp[(size_t)s4.w * 32 + c];
        acc.x = fmaf(w4.x, y0.x, acc.x); acc.y = fmaf(w4.x, y0.y, acc.y);
        acc.z = fmaf(w4.x, y0.z, acc.z); acc.w = fmaf(w4.x, y0.w, acc.w);
        acc.x = fmaf(w4.y, y1.x, acc.x); acc.y = fmaf(w4.y, y1.y, acc.y);
        acc.z = fmaf(w4.y, y1.z, acc.z); acc.w = fmaf(w4.y, y1.w, acc.w);
        acc.x = fmaf(w4.z, y2.x, acc.x); acc.y = fmaf(w4.z, y2.y, acc.y);
        acc.z = fmaf(w4.z, y2.z, acc.z); acc.w = fmaf(w4.z, y2.w, acc.w);
        acc.x = fmaf(w4.w, y3.x, acc.x); acc.y = fmaf(w4.w, y3.y, acc.y);
        acc.z = fmaf(w4.w, y3.z, acc.z); acc.w = fmaf(w4.w, y3.w, acc.w);
    }
    for (; e < e1; ++e) {
        int s0 = ssrc[e]; float w0 = swt[e];
        float4 y0 = *(const float4*)&xp[(size_t)s0 * 32 + c];
        acc.x = fmaf(w0, y0.x, acc.x); acc.y = fmaf(w0, y0.y, acc.y);
        acc.z = fmaf(w0, y0.z, acc.z); acc.w = fmaf(w0, y0.w, acc.w);
    }
    *(float4*)&agg[(size_t)node * 32 + c] = acc;
}

// h1 = relu(agg @ w1_rel + b1 + x @ w1_root), [N,256]; agg/xp padded stride 32.
// k0-step=4 with float4 LDS reads; tail k=28. Per-k chain fmaf(sa,wr,fmaf(sx,wo,.))
// preserved exactly (bit-exact vs previous rounds).
__global__ __launch_bounds__(256) void dense1_kernel(const float* __restrict__ agg,
        const float* __restrict__ xp, const float* __restrict__ wrel,
        const float* __restrict__ wroot, const float* __restrict__ bias,
        float* __restrict__ out) {
    __shared__ float sA[32 * 32];
    __shared__ float sX[32 * 32];
    int tid = threadIdx.x;
    int node0 = blockIdx.x * 32;
    ((float4*)sA)[tid] = ((const float4*)(agg + (size_t)node0 * 32))[tid];
    ((float4*)sX)[tid] = ((const float4*)(xp + (size_t)node0 * 32))[tid];
    __syncthreads();
    int ct = tid & 63;      // 64 col-tiles of 4
    int mg = tid >> 6;      // 4 m-groups of 8 rows
    int c0 = ct * 4;
    float acc[8][4];
#pragma unroll
    for (int m = 0; m < 8; m++)
#pragma unroll
        for (int j = 0; j < 4; j++) acc[m][j] = 0.f;
    for (int k0 = 0; k0 < 28; k0 += 4) {
        float4 wr[4], wo[4];
#pragma unroll
        for (int j = 0; j < 4; j++) {
            wr[j] = *(const float4*)&wrel[(k0 + j) * 256 + c0];
            wo[j] = *(const float4*)&wroot[(k0 + j) * 256 + c0];
        }
#pragma unroll
        for (int m = 0; m < 8; m++) {
            float4 av = *(const float4*)&sA[(mg * 8 + m) * 32 + k0];
            float4 xv = *(const float4*)&sX[(mg * 8 + m) * 32 + k0];
            float as[4] = {av.x, av.y, av.z, av.w};
            float xs[4] = {xv.x, xv.y, xv.z, xv.w};
#pragma unroll
            for (int j = 0; j < 4; j++) {
                acc[m][0] = fmaf(as[j], wr[j].x, fmaf(xs[j], wo[j].x, acc[m][0]));
                acc[m][1] = fmaf(as[j], wr[j].y, fmaf(xs[j], wo[j].y, acc[m][1]));
                acc[m][2] = fmaf(as[j], wr[j].z, fmaf(xs[j], wo[j].z, acc[m][2]));
                acc[m][3] = fmaf(as[j], wr[j].w, fmaf(xs[j], wo[j].w, acc[m][3]));
            }
        }
    }
    {   // tail k = 28
        float4 wr = *(const float4*)&wrel[28 * 256 + c0];
        float4 wo = *(const float4*)&wroot[28 * 256 + c0];
#pragma unroll
        for (int m = 0; m < 8; m++) {
            float sa = sA[(mg * 8 + m) * 32 + 28];
            float sx = sX[(mg * 8 + m) * 32 + 28];
            acc[m][0] = fmaf(sa, wr.x, fmaf(sx, wo.x, acc[m][0]));
            acc[m][1] = fmaf(sa, wr.y, fmaf(sx, wo.y, acc[m][1]));
            acc[m][2] = fmaf(sa, wr.z, fmaf(sx, wo.z, acc[m][2]));
            acc[m][3] = fmaf(sa, wr.w, fmaf(sx, wo.w, acc[m][3]));
        }
    }
    float4 b4 = *(const float4*)&bias[c0];
#pragma unroll
    for (int m = 0; m < 8; m++) {
        int row = node0 + mg * 8 + m;
        float4 o;
        o.x = fmaxf(acc[m][0] + b4.x, 0.f);
        o.y = fmaxf(acc[m][1] + b4.y, 0.f);
        o.z = fmaxf(acc[m][2] + b4.z, 0.f);
        o.w = fmaxf(acc[m][3] + b4.w, 0.f);
        *(float4*)&out[(size_t)row * 256 + c0] = o;
    }
}

// ---------------- dual GEMM: y = in@wA, r = in@wB  ([N,K] @ [K,F]) ----------------
// Round-4 lesson: 16x4 per-thread tile = 1 B LDS per FMA-lane = LDS-BW-bound
// (VALUBusy pinned ~53% across occupancy 18->33%). CPT=8 cols/thread halves LDS
// traffic per FMA; RPM rows x 8 cols per-thread tile, KC-chunked 16 KiB LDS.
// k ascending per output element -> bit-exact vs all previous rounds.
template <int K, int F, int RPM, int KC>
__global__ __launch_bounds__(256) void gemm_dual_kernel(const float* __restrict__ in,
        const float* __restrict__ wA, const float* __restrict__ wB,
        float* __restrict__ outA, float* __restrict__ outB) {
    constexpr int NT = 256;
    constexpr int CPT = 8;            // cols per thread
    constexpr int CQ = CPT / 4;       // float4s per thread-col-tile
    constexpr int NCT = 2 * F / CPT;  // col-groups over the 2F output cols
    constexpr int MG = NT / NCT;      // m-groups
    constexpr int ROWS = MG * RPM;
    constexpr int KC4 = KC / 4;
    __shared__ float s[ROWS * KC];
    int tid = threadIdx.x;
    size_t node0 = (size_t)blockIdx.x * ROWS;
    int ct = tid % NCT;
    int mg = tid / NCT;
    int c0 = ct * CPT;
    const float* W;
    float* OUT;
    int cc;
    if (c0 < F) { W = wA; OUT = outA; cc = c0; }
    else        { W = wB; OUT = outB; cc = c0 - F; }
    float acc[RPM][CPT];
#pragma unroll
    for (int m = 0; m < RPM; m++)
#pragma unroll
        for (int j = 0; j < CPT; j++) acc[m][j] = 0.f;
    const float* srow = s + (size_t)(mg * RPM) * KC;
    for (int kb = 0; kb < K; kb += KC) {
        __syncthreads();
        // stage chunk: rows [node0, node0+ROWS), cols [kb, kb+KC)
        for (int idx = tid; idx < ROWS * KC4; idx += NT) {
            int rr = idx / KC4;
            int c4 = idx % KC4;
            *(float4*)&s[rr * KC + c4 * 4] =
                *(const float4*)&in[(node0 + rr) * K + kb + c4 * 4];
        }
        __syncthreads();
        for (int k0 = 0; k0 < KC; k0 += 4) {
            float4 wv[4][CQ];
#pragma unroll
            for (int j = 0; j < 4; j++)
#pragma unroll
                for (int q = 0; q < CQ; q++)
                    wv[j][q] = *(const float4*)&W[(kb + k0 + j) * F + cc + q * 4];
#pragma unroll
            for (int m = 0; m < RPM; m++) {
                float4 av = *(const float4*)&srow[m * KC + k0];
                float as[4] = {av.x, av.y, av.z, av.w};
#pragma unroll
                for (int j = 0; j < 4; j++) {
#pragma unroll
                    for (int q = 0; q < CQ; q++) {
                        acc[m][q * 4 + 0] = fmaf(as[j], wv[j][q].x, acc[m][q * 4 + 0]);
                        acc[m][q * 4 + 1] = fmaf(as[j], wv[j][q].y, acc[m][q * 4 + 1]);
                        acc[m][q * 4 + 2] = fmaf(as[j], wv[j][q].z, acc[m][q * 4 + 2]);
                        acc[m][q * 4 + 3] = fmaf(as[j], wv[j][q].w, acc[m][q * 4 + 3]);
                    }
                }
            }
        }
    }
#pragma unroll
    for (int m = 0; m < RPM; m++) {
        size_t row = node0 + mg * RPM + m;
#pragma unroll
        for (int q = 0; q < CQ; q++) {
            float4 o = {acc[m][q * 4 + 0], acc[m][q * 4 + 1],
                        acc[m][q * 4 + 2], acc[m][q * 4 + 3]};
            *(float4*)&OUT[row * F + cc + q * 4] = o;
        }
    }
}

// ---------------- combine: h = relu(bn(gather(y) + b + r)) ----------------
// thread owns 4 channels (float4); edge loop: alignment prologue, then x4
// unrolled with vectorized int4/float4 index+weight loads (order-preserving)
template <int F>
__global__ __launch_bounds__(256) void combine_kernel(const float* __restrict__ y,
        const float* __restrict__ r, const int* __restrict__ rowptr,
        const int* __restrict__ ssrc, const float* __restrict__ swt,
        const float* __restrict__ bias, const float* __restrict__ bg,
        const float* __restrict__ bb, const float* __restrict__ bm,
        const float* __restrict__ rs, float* __restrict__ h) {
    constexpr int TPN = F / 4;
    int tid = threadIdx.x;
    int node = blockIdx.x * (256 / TPN) + tid / TPN;
    int c = (tid % TPN) * 4;
    int e0 = rowptr[node], e1 = rowptr[node + 1];
    float4 acc = {0.f, 0.f, 0.f, 0.f};
    int e = e0;
    for (; e < e1 && (e & 3); ++e) {
        int s0 = ssrc[e]; float w0 = swt[e];
        float4 y0 = *(const float4*)&y[(size_t)s0 * F + c];
        acc.x = fmaf(w0, y0.x, acc.x); acc.y = fmaf(w0, y0.y, acc.y);
        acc.z = fmaf(w0, y0.z, acc.z); acc.w = fmaf(w0, y0.w, acc.w);
    }
    for (; e + 4 <= e1; e += 4) {
        int4   s4 = *(const int4*)&ssrc[e];
        float4 w4 = *(const float4*)&swt[e];
        float4 y0 = *(const float4*)&y[(size_t)s4.x * F + c];
        float4 y1 = *(const float4*)&y[(size_t)s4.y * F + c];
        float4 y2 = *(const float4*)&y[(size_t)s4.z * F + c];
        float4 y3 = *(const float4*)&y[(size_t)s4.w * F + c];
        acc.x = fmaf(w4.x, y0.x, acc.x); acc.y = fmaf(w4.x, y0.y, acc.y);
        acc.z = fmaf(w4.x, y0.z, acc.z); acc.w = fmaf(w4.x, y0.w, acc.w);
        acc.x = fmaf(w4.y, y1.x, acc.x); acc.y = fmaf(w4.y, y1.y, acc.y);
        acc.z = fmaf(w4.y, y1.z, acc.z); acc.w = fmaf(w4.y, y1.w, acc.w);
        acc.x = fmaf(w4.z, y2.x, acc.x); acc.y = fmaf(w4.z, y2.y, acc.y);
        acc.z = fmaf(w4.z, y2.z, acc.z); acc.w = fmaf(w4.z, y2.w, acc.w);
        acc.x = fmaf(w4.w, y3.x, acc.x); acc.y = fmaf(w4.w, y3.y, acc.y);
        acc.z = fmaf(w4.w, y3.z, acc.z); acc.w = fmaf(w4.w, y3.w, acc.w);
    }
    for (; e < e1; ++e) {
        int s0 = ssrc[e]; float w0 = swt[e];
        float4 y0 = *(const float4*)&y[(size_t)s0 * F + c];
        acc.x = fmaf(w0, y0.x, acc.x); acc.y = fmaf(w0, y0.y, acc.y);
        acc.z = fmaf(w0, y0.z, acc.z); acc.w = fmaf(w0, y0.w, acc.w);
    }
    float4 bi = *(const float4*)&bias[c];
    float4 rv = *(const float4*)&r[(size_t)node * F + c];
    float4 mu = *(const float4*)&bm[c];
    float4 rq = *(const float4*)&rs[c];
    float4 gm = *(const float4*)&bg[c];
    float4 bt = *(const float4*)&bb[c];
    float4 o;
    o.x = fmaxf((acc.x + bi.x + rv.x - mu.x) * rq.x * gm.x + bt.x, 0.f);
    o.y = fmaxf((acc.y + bi.y + rv.y - mu.y) * rq.y * gm.y + bt.y, 0.f);
    o.z = fmaxf((acc.z + bi.z + rv.z - mu.z) * rq.z * gm.z + bt.z, 0.f);
    o.w = fmaxf((acc.w + bi.w + rv.w - mu.w) * rq.w * gm.w + bt.w, 0.f);
    *(float4*)&h[(size_t)node * F + c] = o;
}

// ---------------- pool + fc + sigmoid ----------------
__global__ __launch_bounds__(256) void pool_fc_kernel(const float* __restrict__ h4,
        const int* __restrict__ starts, const float* __restrict__ fcw,
        const float* __restrict__ fcb, float* __restrict__ out) {
    int g = blockIdx.x;
    int tid = threadIdx.x;
    int i0 = starts[g], i1 = starts[g + 1];
    int ch = tid & 31, part = tid >> 5;
    float sum = 0.f;
    for (int i = i0 + part; i < i1; i += 8) sum += h4[(size_t)i * 32 + ch];
    __shared__ float sm[8][32];
    sm[part][ch] = sum;
    __syncthreads();
    if (tid < 32) {
        float tot = 0.f;
        for (int p = 0; p < 8; p++) tot += sm[p][tid];
        float cnt = (float)(i1 - i0);
        float mean = tot / fmaxf(cnt, 1.0f);
        sm[0][tid] = mean * fcw[tid];
    }
    __syncthreads();
    if (tid == 0) {
        float z = 0.f;
        for (int c = 0; c < 32; c++) z += sm[0][c];
        z += fcb[0];
        out[g] = 1.0f / (1.0f + expf(-z));
    }
}

extern "C" void kernel_launch(void* const* d_in, const int* in_sizes, int n_in,
                              void* d_out, int out_size, void* d_ws, size_t ws_size,
                              hipStream_t stream) {
    (void)in_sizes; (void)n_in; (void)out_size; (void)ws_size;
    const float* x       = (const float*)d_in[0];
    const int*   ei      = (const int*)d_in[1];
    const float* ew      = (const float*)d_in[2];
    const int*   batch   = (const int*)d_in[3];
    const float* w1_rel  = (const float*)d_in[4];
    const float* b1      = (const float*)d_in[5];
    const float* w1_root = (const float*)d_in[6];
    const float* w2_rel  = (const float*)d_in[7];
    const float* b2      = (const float*)d_in[8];
    const float* w2_root = (const float*)d_in[9];
    const float* w3_rel  = (const float*)d_in[10];
    const float* b3      = (const float*)d_in[11];
    const float* w3_root = (const float*)d_in[12];
    const float* w4_rel  = (const float*)d_in[13];
    const float* b4      = (const float*)d_in[14];
    const float* w4_root = (const float*)d_in[15];
    const float* bn1_g = (const float*)d_in[16];
    const float* bn1_b = (const float*)d_in[17];
    const float* bn1_m = (const float*)d_in[18];
    const float* bn2_g = (const float*)d_in[20];
    const float* bn2_b = (const float*)d_in[21];
    const float* bn2_m = (const float*)d_in[22];
    const float* bn3_g = (const float*)d_in[24];
    const float* bn3_b = (const float*)d_in[25];
    const float* bn3_m = (const float*)d_in[26];
    const float* fc_w = (const float*)d_in[28];
    const float* fc_b = (const float*)d_in[29];

    char* ws = (char*)d_ws;
    int*   rowptr = (int*)(ws + 0);                              // (N+1)*4
    int*   cnt    = (int*)(ws + (1ull << 20));                   // N*4
    int*   bsum   = (int*)(ws + (2ull << 20));                   // 391*4
    float* rs     = (float*)(ws + (2ull << 20) + (64ull << 10)); // 224 floats
    int*   starts = (int*)(ws + (2ull << 20) + (128ull << 10));  // 257*4
    int*   ssrc   = (int*)(ws + (4ull << 20));                   // E*4 = 6.4MB
    float* swt    = (float*)(ws + (11ull << 20));                // E*4 = 6.4MB
    float* bufA   = (float*)(ws + (18ull << 20));                // 104MB: h1 / r3,h3
    float* bufB   = (float*)(ws + (122ull << 20));               // 52MB:  xp / y2 / y3 / y4
    float* bufC   = (float*)(ws + (174ull << 20));               // 52MB:  agg / r2,h2 / r4,h4
    float* xp   = bufB;   // [N,32] padded x; dead before gemm2 writes bufB
    float* agg1 = bufC;   // [N,32] padded agg; dead before gemm2 writes bufC

    // CSR build (reused by all 4 layers)
    hipMemsetAsync(cnt, 0, N_NODES * 4, stream);
    hist_kernel<<<6250, 256, 0, stream>>>(ei, cnt);
    scan1_kernel<<<391, 256, 0, stream>>>(cnt, rowptr, bsum);
    scan2_kernel<<<1, 512, 0, stream>>>(bsum, 391);
    scan3_kernel<<<391, 256, 0, stream>>>(rowptr, bsum);
    hipMemsetAsync(cnt, 0, N_NODES * 4, stream);
    scatter_kernel<<<6250, 256, 0, stream>>>(ei, ew, rowptr, cnt, ssrc, swt);
    bnprep_kernel<<<1, 128, 0, stream>>>((const float*)d_in[19], (const float*)d_in[23],
                                         (const float*)d_in[27], rs);
    starts_kernel<<<391, 256, 0, stream>>>(batch, starts);

    // layer 1 (29 -> 256), aggregate-first on padded x
    pad_x_kernel<<<12500, 256, 0, stream>>>(x, xp);
    agg_x_kernel<<<3125, 256, 0, stream>>>(xp, rowptr, ssrc, swt, agg1);
    dense1_kernel<<<3125, 256, 0, stream>>>(agg1, xp, w1_rel, w1_root, b1, bufA);

    // layer 2 (256 -> 128): NCT=32, MG=8, RPM=8 -> ROWS=64; KC=64 -> 16 KiB LDS
    gemm_dual_kernel<256, 128, 8, 64><<<1563, 256, 0, stream>>>(bufA, w2_rel, w2_root, bufB, bufC);
    combine_kernel<128><<<12500, 256, 0, stream>>>(bufB, bufC, rowptr, ssrc, swt,
                                                   b2, bn1_g, bn1_b, bn1_m, rs, bufC);

    // layer 3 (128 -> 64): NCT=16, MG=16, RPM=4 -> ROWS=64; KC=64 -> 16 KiB LDS
    gemm_dual_kernel<128, 64, 4, 64><<<1563, 256, 0, stream>>>(bufC, w3_rel, w3_root, bufB, bufA);
    combine_kernel<64><<<6250, 256, 0, stream>>>(bufB, bufA, rowptr, ssrc, swt,
                                                 b3, bn2_g, bn2_b, bn2_m, rs + 128, bufA);

    // layer 4 (64 -> 32): NCT=8, MG=32, RPM=4 -> ROWS=128; KC=32 -> 16 KiB LDS
    gemm_dual_kernel<64, 32, 4, 32><<<782, 256, 0, stream>>>(bufA, w4_rel, w4_root, bufB, bufC);
    combine_kernel<32><<<3125, 256, 0, stream>>>(bufB, bufC, rowptr, ssrc, swt,
                                                 b4, bn3_g, bn3_b, bn3_m, rs + 192, bufC);

    // pool + fc + sigmoid
    pool_fc_kernel<<<N_GRAPHS, 256, 0, stream>>>(bufC, starts, fc_w, fc_b, (float*)d_out);
}

// Round 6
// 816.014 us; speedup vs baseline: 1.0534x; 1.0534x over previous
//
#include <hip/hip_runtime.h>
#include <math.h>

#define N_NODES 100000
#define N_EDGES 1600000
#define N_GRAPHS 256
#define BN_EPS 1e-5f

// ---------------- CSR build ----------------
__global__ void hist_kernel(const int* __restrict__ ei, int* __restrict__ deg) {
    int e = blockIdx.x * blockDim.x + threadIdx.x;
    if (e < N_EDGES) atomicAdd(&deg[ei[N_EDGES + e]], 1);
}

__global__ void scan1_kernel(const int* __restrict__ deg, int* __restrict__ rowptr,
                             int* __restrict__ bsum) {
    __shared__ int s[256];
    int tid = threadIdx.x;
    int i = blockIdx.x * 256 + tid;
    int v = (i < N_NODES) ? deg[i] : 0;
    s[tid] = v; __syncthreads();
    for (int off = 1; off < 256; off <<= 1) {
        int t = (tid >= off) ? s[tid - off] : 0; __syncthreads();
        s[tid] += t; __syncthreads();
    }
    if (i < N_NODES) rowptr[i] = s[tid] - v;   // exclusive
    if (tid == 255) bsum[blockIdx.x] = s[255];
}

__global__ void scan2_kernel(int* bsum, int nb) {
    __shared__ int s[512];
    int tid = threadIdx.x;
    int v = (tid < nb) ? bsum[tid] : 0;
    s[tid] = v; __syncthreads();
    for (int off = 1; off < 512; off <<= 1) {
        int t = (tid >= off) ? s[tid - off] : 0; __syncthreads();
        s[tid] += t; __syncthreads();
    }
    if (tid < nb) bsum[tid] = s[tid] - v;      // exclusive
}

__global__ void scan3_kernel(int* __restrict__ rowptr, const int* __restrict__ bsum) {
    int i = blockIdx.x * 256 + threadIdx.x;
    if (i < N_NODES) rowptr[i] += bsum[blockIdx.x];
    if (i == 0) rowptr[N_NODES] = N_EDGES;
}

__global__ void scatter_kernel(const int* __restrict__ ei, const float* __restrict__ ew,
                               const int* __restrict__ rowptr, int* __restrict__ cnt,
                               int* __restrict__ ssrc, float* __restrict__ swt) {
    int e = blockIdx.x * blockDim.x + threadIdx.x;
    if (e >= N_EDGES) return;
    int dst = ei[N_EDGES + e];
    int pos = rowptr[dst] + atomicAdd(&cnt[dst], 1);
    ssrc[pos] = ei[e];
    swt[pos] = ew[e];
}

// ---------------- misc precompute ----------------
__global__ void bnprep_kernel(const float* __restrict__ v1, const float* __restrict__ v2,
                              const float* __restrict__ v3, float* __restrict__ rs) {
    int t = threadIdx.x;
    if (t < 128) rs[t] = 1.0f / sqrtf(v1[t] + BN_EPS);
    if (t < 64)  rs[128 + t] = 1.0f / sqrtf(v2[t] + BN_EPS);
    if (t < 32)  rs[192 + t] = 1.0f / sqrtf(v3[t] + BN_EPS);
}

__global__ void starts_kernel(const int* __restrict__ batch, int* __restrict__ starts) {
    int i = blockIdx.x * 256 + threadIdx.x;
    if (i >= N_NODES) return;
    int b = batch[i];
    int bp = (i == 0) ? -1 : batch[i - 1];
    for (int g = bp + 1; g <= b; ++g) starts[g] = i;
    if (i == N_NODES - 1)
        for (int g = b + 1; g <= N_GRAPHS; ++g) starts[g] = N_NODES;
}

// pad x [N,29] -> xp [N,32] (zeros in 29..31)
__global__ __launch_bounds__(256) void pad_x_kernel(const float* __restrict__ x,
                                                    float* __restrict__ xp) {
    int i = blockIdx.x * 256 + threadIdx.x;
    if (i >= N_NODES * 32) return;
    int n = i >> 5, c = i & 31;
    xp[i] = (c < 29) ? x[n * 29 + c] : 0.f;
}

// ---------------- layer-1 gather on padded x: agg[N,32] ----------------
__global__ __launch_bounds__(256) void agg_x_kernel(const float* __restrict__ xp,
        const int* __restrict__ rowptr, const int* __restrict__ ssrc,
        const float* __restrict__ swt, float* __restrict__ agg) {
    int tid = threadIdx.x;
    int node = blockIdx.x * 32 + (tid >> 3);
    int c = (tid & 7) * 4;
    int e0 = rowptr[node], e1 = rowptr[node + 1];
    float4 acc = {0.f, 0.f, 0.f, 0.f};
    int e = e0;
    // align e to 4 (order-preserving)
    for (; e < e1 && (e & 3); ++e) {
        int s0 = ssrc[e]; float w0 = swt[e];
        float4 y0 = *(const float4*)&xp[(size_t)s0 * 32 + c];
        acc.x = fmaf(w0, y0.x, acc.x); acc.y = fmaf(w0, y0.y, acc.y);
        acc.z = fmaf(w0, y0.z, acc.z); acc.w = fmaf(w0, y0.w, acc.w);
    }
    for (; e + 4 <= e1; e += 4) {
        int4   s4 = *(const int4*)&ssrc[e];
        float4 w4 = *(const float4*)&swt[e];
        float4 y0 = *(const float4*)&xp[(size_t)s4.x * 32 + c];
        float4 y1 = *(const float4*)&xp[(size_t)s4.y * 32 + c];
        float4 y2 = *(const float4*)&xp[(size_t)s4.z * 32 + c];
        float4 y3 = *(const float4*)&xp[(size_t)s4.w * 32 + c];
        acc.x = fmaf(w4.x, y0.x, acc.x); acc.y = fmaf(w4.x, y0.y, acc.y);
        acc.z = fmaf(w4.x, y0.z, acc.z); acc.w = fmaf(w4.x, y0.w, acc.w);
        acc.x = fmaf(w4.y, y1.x, acc.x); acc.y = fmaf(w4.y, y1.y, acc.y);
        acc.z = fmaf(w4.y, y1.z, acc.z); acc.w = fmaf(w4.y, y1.w, acc.w);
        acc.x = fmaf(w4.z, y2.x, acc.x); acc.y = fmaf(w4.z, y2.y, acc.y);
        acc.z = fmaf(w4.z, y2.z, acc.z); acc.w = fmaf(w4.z, y2.w, acc.w);
        acc.x = fmaf(w4.w, y3.x, acc.x); acc.y = fmaf(w4.w, y3.y, acc.y);
        acc.z = fmaf(w4.w, y3.z, acc.z); acc.w = fmaf(w4.w, y3.w, acc.w);
    }
    for (; e < e1; ++e) {
        int s0 = ssrc[e]; float w0 = swt[e];
        float4 y0 = *(const float4*)&xp[(size_t)s0 * 32 + c];
        acc.x = fmaf(w0, y0.x, acc.x); acc.y = fmaf(w0, y0.y, acc.y);
        acc.z = fmaf(w0, y0.z, acc.z); acc.w = fmaf(w0, y0.w, acc.w);
    }
    *(float4*)&agg[(size_t)node * 32 + c] = acc;
}

// h1 = relu(agg @ w1_rel + b1 + x @ w1_root), [N,256]; agg/xp padded stride 32.
__global__ __launch_bounds__(256) void dense1_kernel(const float* __restrict__ agg,
        const float* __restrict__ xp, const float* __restrict__ wrel,
        const float* __restrict__ wroot, const float* __restrict__ bias,
        float* __restrict__ out) {
    __shared__ float sA[32 * 32];
    __shared__ float sX[32 * 32];
    int tid = threadIdx.x;
    int node0 = blockIdx.x * 32;
    ((float4*)sA)[tid] = ((const float4*)(agg + (size_t)node0 * 32))[tid];
    ((float4*)sX)[tid] = ((const float4*)(xp + (size_t)node0 * 32))[tid];
    __syncthreads();
    int ct = tid & 63;      // 64 col-tiles of 4
    int mg = tid >> 6;      // 4 m-groups of 8 rows
    int c0 = ct * 4;
    float acc[8][4];
#pragma unroll
    for (int m = 0; m < 8; m++)
#pragma unroll
        for (int j = 0; j < 4; j++) acc[m][j] = 0.f;
    for (int k0 = 0; k0 < 28; k0 += 4) {
        float4 wr[4], wo[4];
#pragma unroll
        for (int j = 0; j < 4; j++) {
            wr[j] = *(const float4*)&wrel[(k0 + j) * 256 + c0];
            wo[j] = *(const float4*)&wroot[(k0 + j) * 256 + c0];
        }
#pragma unroll
        for (int m = 0; m < 8; m++) {
            float4 av = *(const float4*)&sA[(mg * 8 + m) * 32 + k0];
            float4 xv = *(const float4*)&sX[(mg * 8 + m) * 32 + k0];
            float as[4] = {av.x, av.y, av.z, av.w};
            float xs[4] = {xv.x, xv.y, xv.z, xv.w};
#pragma unroll
            for (int j = 0; j < 4; j++) {
                acc[m][0] = fmaf(as[j], wr[j].x, fmaf(xs[j], wo[j].x, acc[m][0]));
                acc[m][1] = fmaf(as[j], wr[j].y, fmaf(xs[j], wo[j].y, acc[m][1]));
                acc[m][2] = fmaf(as[j], wr[j].z, fmaf(xs[j], wo[j].z, acc[m][2]));
                acc[m][3] = fmaf(as[j], wr[j].w, fmaf(xs[j], wo[j].w, acc[m][3]));
            }
        }
    }
    {   // tail k = 28
        float4 wr = *(const float4*)&wrel[28 * 256 + c0];
        float4 wo = *(const float4*)&wroot[28 * 256 + c0];
#pragma unroll
        for (int m = 0; m < 8; m++) {
            float sa = sA[(mg * 8 + m) * 32 + 28];
            float sx = sX[(mg * 8 + m) * 32 + 28];
            acc[m][0] = fmaf(sa, wr.x, fmaf(sx, wo.x, acc[m][0]));
            acc[m][1] = fmaf(sa, wr.y, fmaf(sx, wo.y, acc[m][1]));
            acc[m][2] = fmaf(sa, wr.z, fmaf(sx, wo.z, acc[m][2]));
            acc[m][3] = fmaf(sa, wr.w, fmaf(sx, wo.w, acc[m][3]));
        }
    }
    float4 b4 = *(const float4*)&bias[c0];
#pragma unroll
    for (int m = 0; m < 8; m++) {
        int row = node0 + mg * 8 + m;
        float4 o;
        o.x = fmaxf(acc[m][0] + b4.x, 0.f);
        o.y = fmaxf(acc[m][1] + b4.y, 0.f);
        o.z = fmaxf(acc[m][2] + b4.z, 0.f);
        o.w = fmaxf(acc[m][3] + b4.w, 0.f);
        *(float4*)&out[(size_t)row * 256 + c0] = o;
    }
}

// ---------------- dual GEMM: y = in@wA, r = in@wB  ([N,K] @ [K,F]) ----------------
// R5 post-mortem: A-fragment LDS reads are wave-uniform broadcasts (cheap);
// the binding constraint is the W global-load stream's latency exposed after
// each barrier. Fixes here: (1) W register double-buffer — prefetch step
// k0+4's weights while FMA-ing step k0 (k0 loop fully unrolled: all wv
// indices compile-time, rule-#20 safe); (2) A-chunk double-buffered LDS with
// async reg staging (issue next chunk's loads at chunk top, ds_write after
// compute, ONE barrier per chunk). FMA consumption order unchanged -> bit-exact.
template <int K, int F, int RPM, int KC>
__global__ __launch_bounds__(256) void gemm_dual_kernel(const float* __restrict__ in,
        const float* __restrict__ wA, const float* __restrict__ wB,
        float* __restrict__ outA, float* __restrict__ outB) {
    constexpr int NT = 256;
    constexpr int NCT = F / 2;        // 4 cols per thread over 2F outputs
    constexpr int MG = NT / NCT;
    constexpr int ROWS = MG * RPM;
    constexpr int KC4 = KC / 4;
    constexpr int LPT = (ROWS * KC4) / NT;   // stage float4s per thread
    __shared__ float sbuf[2][ROWS * KC];
    int tid = threadIdx.x;
    size_t node0 = (size_t)blockIdx.x * ROWS;
    int ct = tid % NCT;
    int mg = tid / NCT;
    int c0 = ct * 4;
    const float* W;
    float* OUT;
    int cc;
    if (c0 < F) { W = wA; OUT = outA; cc = c0; }
    else        { W = wB; OUT = outB; cc = c0 - F; }
    float acc[RPM][4];
#pragma unroll
    for (int m = 0; m < RPM; m++)
#pragma unroll
        for (int j = 0; j < 4; j++) acc[m][j] = 0.f;

    // prologue: stage chunk 0 into sbuf[0]; preload W step 0
#pragma unroll
    for (int i = 0; i < LPT; i++) {
        int idx = tid + i * NT;
        int rr = idx / KC4, c4 = idx % KC4;
        *(float4*)&sbuf[0][rr * KC + c4 * 4] =
            *(const float4*)&in[(node0 + rr) * K + c4 * 4];
    }
    float4 wv[2][4];
#pragma unroll
    for (int j = 0; j < 4; j++) wv[0][j] = *(const float4*)&W[j * F + cc];
    __syncthreads();

    int cur = 0;
#pragma unroll 1
    for (int kb = 0; kb < K; kb += KC) {
        const bool more = (kb + KC < K);
        // issue next-chunk A loads into registers (async; completes under compute)
        float4 st[LPT];
        if (more) {
#pragma unroll
            for (int i = 0; i < LPT; i++) {
                int idx = tid + i * NT;
                int rr = idx / KC4, c4 = idx % KC4;
                st[i] = *(const float4*)&in[(node0 + rr) * K + (kb + KC) + c4 * 4];
            }
        }
        const float* srow = &sbuf[cur][0] + (size_t)(mg * RPM) * KC;
#pragma unroll
        for (int k0 = 0; k0 < KC; k0 += 4) {
            const int pf = (k0 / 4) & 1;     // compile-time after unroll
            const int nx = pf ^ 1;
            int kn = kb + k0 + 4;
            if (kn < K) {                    // prefetch next step's W
#pragma unroll
                for (int j = 0; j < 4; j++)
                    wv[nx][j] = *(const float4*)&W[(size_t)(kn + j) * F + cc];
            }
#pragma unroll
            for (int m = 0; m < RPM; m++) {
                float4 sm = *(const float4*)&srow[m * KC + k0];
                acc[m][0] = fmaf(sm.x, wv[pf][0].x, acc[m][0]);
                acc[m][1] = fmaf(sm.x, wv[pf][0].y, acc[m][1]);
                acc[m][2] = fmaf(sm.x, wv[pf][0].z, acc[m][2]);
                acc[m][3] = fmaf(sm.x, wv[pf][0].w, acc[m][3]);
                acc[m][0] = fmaf(sm.y, wv[pf][1].x, acc[m][0]);
                acc[m][1] = fmaf(sm.y, wv[pf][1].y, acc[m][1]);
                acc[m][2] = fmaf(sm.y, wv[pf][1].z, acc[m][2]);
                acc[m][3] = fmaf(sm.y, wv[pf][1].w, acc[m][3]);
                acc[m][0] = fmaf(sm.z, wv[pf][2].x, acc[m][0]);
                acc[m][1] = fmaf(sm.z, wv[pf][2].y, acc[m][1]);
                acc[m][2] = fmaf(sm.z, wv[pf][2].z, acc[m][2]);
                acc[m][3] = fmaf(sm.z, wv[pf][2].w, acc[m][3]);
                acc[m][0] = fmaf(sm.w, wv[pf][3].x, acc[m][0]);
                acc[m][1] = fmaf(sm.w, wv[pf][3].y, acc[m][1]);
                acc[m][2] = fmaf(sm.w, wv[pf][3].z, acc[m][2]);
                acc[m][3] = fmaf(sm.w, wv[pf][3].w, acc[m][3]);
            }
        }
        if (more) {
            float* dbuf = &sbuf[cur ^ 1][0];
#pragma unroll
            for (int i = 0; i < LPT; i++) {
                int idx = tid + i * NT;
                int rr = idx / KC4, c4 = idx % KC4;
                *(float4*)&dbuf[rr * KC + c4 * 4] = st[i];
            }
            cur ^= 1;
            __syncthreads();
        }
    }
#pragma unroll
    for (int m = 0; m < RPM; m++) {
        size_t row = node0 + mg * RPM + m;
        float4 o = {acc[m][0], acc[m][1], acc[m][2], acc[m][3]};
        *(float4*)&OUT[row * F + cc] = o;
    }
}

// ---------------- combine: h = relu(bn(gather(y) + b + r)) ----------------
template <int F>
__global__ __launch_bounds__(256) void combine_kernel(const float* __restrict__ y,
        const float* __restrict__ r, const int* __restrict__ rowptr,
        const int* __restrict__ ssrc, const float* __restrict__ swt,
        const float* __restrict__ bias, const float* __restrict__ bg,
        const float* __restrict__ bb, const float* __restrict__ bm,
        const float* __restrict__ rs, float* __restrict__ h) {
    constexpr int TPN = F / 4;
    int tid = threadIdx.x;
    int node = blockIdx.x * (256 / TPN) + tid / TPN;
    int c = (tid % TPN) * 4;
    int e0 = rowptr[node], e1 = rowptr[node + 1];
    float4 acc = {0.f, 0.f, 0.f, 0.f};
    int e = e0;
    for (; e < e1 && (e & 3); ++e) {
        int s0 = ssrc[e]; float w0 = swt[e];
        float4 y0 = *(const float4*)&y[(size_t)s0 * F + c];
        acc.x = fmaf(w0, y0.x, acc.x); acc.y = fmaf(w0, y0.y, acc.y);
        acc.z = fmaf(w0, y0.z, acc.z); acc.w = fmaf(w0, y0.w, acc.w);
    }
    for (; e + 4 <= e1; e += 4) {
        int4   s4 = *(const int4*)&ssrc[e];
        float4 w4 = *(const float4*)&swt[e];
        float4 y0 = *(const float4*)&y[(size_t)s4.x * F + c];
        float4 y1 = *(const float4*)&y[(size_t)s4.y * F + c];
        float4 y2 = *(const float4*)&y[(size_t)s4.z * F + c];
        float4 y3 = *(const float4*)&y[(size_t)s4.w * F + c];
        acc.x = fmaf(w4.x, y0.x, acc.x); acc.y = fmaf(w4.x, y0.y, acc.y);
        acc.z = fmaf(w4.x, y0.z, acc.z); acc.w = fmaf(w4.x, y0.w, acc.w);
        acc.x = fmaf(w4.y, y1.x, acc.x); acc.y = fmaf(w4.y, y1.y, acc.y);
        acc.z = fmaf(w4.y, y1.z, acc.z); acc.w = fmaf(w4.y, y1.w, acc.w);
        acc.x = fmaf(w4.z, y2.x, acc.x); acc.y = fmaf(w4.z, y2.y, acc.y);
        acc.z = fmaf(w4.z, y2.z, acc.z); acc.w = fmaf(w4.z, y2.w, acc.w);
        acc.x = fmaf(w4.w, y3.x, acc.x); acc.y = fmaf(w4.w, y3.y, acc.y);
        acc.z = fmaf(w4.w, y3.z, acc.z); acc.w = fmaf(w4.w, y3.w, acc.w);
    }
    for (; e < e1; ++e) {
        int s0 = ssrc[e]; float w0 = swt[e];
        float4 y0 = *(const float4*)&y[(size_t)s0 * F + c];
        acc.x = fmaf(w0, y0.x, acc.x); acc.y = fmaf(w0, y0.y, acc.y);
        acc.z = fmaf(w0, y0.z, acc.z); acc.w = fmaf(w0, y0.w, acc.w);
    }
    float4 bi = *(const float4*)&bias[c];
    float4 rv = *(const float4*)&r[(size_t)node * F + c];
    float4 mu = *(const float4*)&bm[c];
    float4 rq = *(const float4*)&rs[c];
    float4 gm = *(const float4*)&bg[c];
    float4 bt = *(const float4*)&bb[c];
    float4 o;
    o.x = fmaxf((acc.x + bi.x + rv.x - mu.x) * rq.x * gm.x + bt.x, 0.f);
    o.y = fmaxf((acc.y + bi.y + rv.y - mu.y) * rq.y * gm.y + bt.y, 0.f);
    o.z = fmaxf((acc.z + bi.z + rv.z - mu.z) * rq.z * gm.z + bt.z, 0.f);
    o.w = fmaxf((acc.w + bi.w + rv.w - mu.w) * rq.w * gm.w + bt.w, 0.f);
    *(float4*)&h[(size_t)node * F + c] = o;
}

// ---------------- pool + fc + sigmoid ----------------
__global__ __launch_bounds__(256) void pool_fc_kernel(const float* __restrict__ h4,
        const int* __restrict__ starts, const float* __restrict__ fcw,
        const float* __restrict__ fcb, float* __restrict__ out) {
    int g = blockIdx.x;
    int tid = threadIdx.x;
    int i0 = starts[g], i1 = starts[g + 1];
    int ch = tid & 31, part = tid >> 5;
    float sum = 0.f;
    for (int i = i0 + part; i < i1; i += 8) sum += h4[(size_t)i * 32 + ch];
    __shared__ float sm[8][32];
    sm[part][ch] = sum;
    __syncthreads();
    if (tid < 32) {
        float tot = 0.f;
        for (int p = 0; p < 8; p++) tot += sm[p][tid];
        float cnt = (float)(i1 - i0);
        float mean = tot / fmaxf(cnt, 1.0f);
        sm[0][tid] = mean * fcw[tid];
    }
    __syncthreads();
    if (tid == 0) {
        float z = 0.f;
        for (int c = 0; c < 32; c++) z += sm[0][c];
        z += fcb[0];
        out[g] = 1.0f / (1.0f + expf(-z));
    }
}

extern "C" void kernel_launch(void* const* d_in, const int* in_sizes, int n_in,
                              void* d_out, int out_size, void* d_ws, size_t ws_size,
                              hipStream_t stream) {
    (void)in_sizes; (void)n_in; (void)out_size; (void)ws_size;
    const float* x       = (const float*)d_in[0];
    const int*   ei      = (const int*)d_in[1];
    const float* ew      = (const float*)d_in[2];
    const int*   batch   = (const int*)d_in[3];
    const float* w1_rel  = (const float*)d_in[4];
    const float* b1      = (const float*)d_in[5];
    const float* w1_root = (const float*)d_in[6];
    const float* w2_rel  = (const float*)d_in[7];
    const float* b2      = (const float*)d_in[8];
    const float* w2_root = (const float*)d_in[9];
    const float* w3_rel  = (const float*)d_in[10];
    const float* b3      = (const float*)d_in[11];
    const float* w3_root = (const float*)d_in[12];
    const float* w4_rel  = (const float*)d_in[13];
    const float* b4      = (const float*)d_in[14];
    const float* w4_root = (const float*)d_in[15];
    const float* bn1_g = (const float*)d_in[16];
    const float* bn1_b = (const float*)d_in[17];
    const float* bn1_m = (const float*)d_in[18];
    const float* bn2_g = (const float*)d_in[20];
    const float* bn2_b = (const float*)d_in[21];
    const float* bn2_m = (const float*)d_in[22];
    const float* bn3_g = (const float*)d_in[24];
    const float* bn3_b = (const float*)d_in[25];
    const float* bn3_m = (const float*)d_in[26];
    const float* fc_w = (const float*)d_in[28];
    const float* fc_b = (const float*)d_in[29];

    char* ws = (char*)d_ws;
    int*   rowptr = (int*)(ws + 0);                              // (N+1)*4
    int*   cnt    = (int*)(ws + (1ull << 20));                   // N*4
    int*   bsum   = (int*)(ws + (2ull << 20));                   // 391*4
    float* rs     = (float*)(ws + (2ull << 20) + (64ull << 10)); // 224 floats
    int*   starts = (int*)(ws + (2ull << 20) + (128ull << 10));  // 257*4
    int*   ssrc   = (int*)(ws + (4ull << 20));                   // E*4 = 6.4MB
    float* swt    = (float*)(ws + (11ull << 20));                // E*4 = 6.4MB
    float* bufA   = (float*)(ws + (18ull << 20));                // 104MB: h1 / r3,h3
    float* bufB   = (float*)(ws + (122ull << 20));               // 52MB:  xp / y2 / y3 / y4
    float* bufC   = (float*)(ws + (174ull << 20));               // 52MB:  agg / r2,h2 / r4,h4
    float* xp   = bufB;   // [N,32] padded x; dead before gemm2 writes bufB
    float* agg1 = bufC;   // [N,32] padded agg; dead before gemm2 writes bufC

    // CSR build (reused by all 4 layers)
    hipMemsetAsync(cnt, 0, N_NODES * 4, stream);
    hist_kernel<<<6250, 256, 0, stream>>>(ei, cnt);
    scan1_kernel<<<391, 256, 0, stream>>>(cnt, rowptr, bsum);
    scan2_kernel<<<1, 512, 0, stream>>>(bsum, 391);
    scan3_kernel<<<391, 256, 0, stream>>>(rowptr, bsum);
    hipMemsetAsync(cnt, 0, N_NODES * 4, stream);
    scatter_kernel<<<6250, 256, 0, stream>>>(ei, ew, rowptr, cnt, ssrc, swt);
    bnprep_kernel<<<1, 128, 0, stream>>>((const float*)d_in[19], (const float*)d_in[23],
                                         (const float*)d_in[27], rs);
    starts_kernel<<<391, 256, 0, stream>>>(batch, starts);

    // layer 1 (29 -> 256), aggregate-first on padded x
    pad_x_kernel<<<12500, 256, 0, stream>>>(x, xp);
    agg_x_kernel<<<3125, 256, 0, stream>>>(xp, rowptr, ssrc, swt, agg1);
    dense1_kernel<<<3125, 256, 0, stream>>>(agg1, xp, w1_rel, w1_root, b1, bufA);

    // layer 2 (256 -> 128): NCT=64, MG=4, RPM=16 -> ROWS=64; KC=64, 2x16 KiB LDS
    gemm_dual_kernel<256, 128, 16, 64><<<1563, 256, 0, stream>>>(bufA, w2_rel, w2_root, bufB, bufC);
    combine_kernel<128><<<12500, 256, 0, stream>>>(bufB, bufC, rowptr, ssrc, swt,
                                                   b2, bn1_g, bn1_b, bn1_m, rs, bufC);

    // layer 3 (128 -> 64): NCT=32, MG=8, RPM=8 -> ROWS=64; KC=64, 2x16 KiB LDS
    gemm_dual_kernel<128, 64, 8, 64><<<1563, 256, 0, stream>>>(bufC, w3_rel, w3_root, bufB, bufA);
    combine_kernel<64><<<6250, 256, 0, stream>>>(bufB, bufA, rowptr, ssrc, swt,
                                                 b3, bn2_g, bn2_b, bn2_m, rs + 128, bufA);

    // layer 4 (64 -> 32): NCT=16, MG=16, RPM=4 -> ROWS=64; KC=32, 2x8 KiB LDS
    gemm_dual_kernel<64, 32, 4, 32><<<1563, 256, 0, stream>>>(bufA, w4_rel, w4_root, bufB, bufC);
    combine_kernel<32><<<3125, 256, 0, stream>>>(bufB, bufC, rowptr, ssrc, swt,
                                                 b4, bn3_g, bn3_b, bn3_m, rs + 192, bufC);

    // pool + fc + sigmoid
    pool_fc_kernel<<<N_GRAPHS, 256, 0, stream>>>(bufC, starts, fc_w, fc_b, (float*)d_out);
}

// Round 7
// 795.048 us; speedup vs baseline: 1.0812x; 1.0264x over previous
//
#include <hip/hip_runtime.h>
#include <math.h>

#define N_NODES 100000
#define N_EDGES 1600000
#define N_GRAPHS 256
#define BN_EPS 1e-5f

// ---------------- CSR build ----------------
__global__ void hist_kernel(const int* __restrict__ ei, int* __restrict__ deg) {
    int e = blockIdx.x * blockDim.x + threadIdx.x;
    if (e < N_EDGES) atomicAdd(&deg[ei[N_EDGES + e]], 1);
}

__global__ void scan1_kernel(const int* __restrict__ deg, int* __restrict__ rowptr,
                             int* __restrict__ bsum) {
    __shared__ int s[256];
    int tid = threadIdx.x;
    int i = blockIdx.x * 256 + tid;
    int v = (i < N_NODES) ? deg[i] : 0;
    s[tid] = v; __syncthreads();
    for (int off = 1; off < 256; off <<= 1) {
        int t = (tid >= off) ? s[tid - off] : 0; __syncthreads();
        s[tid] += t; __syncthreads();
    }
    if (i < N_NODES) rowptr[i] = s[tid] - v;   // exclusive
    if (tid == 255) bsum[blockIdx.x] = s[255];
}

__global__ void scan2_kernel(int* bsum, int nb) {
    __shared__ int s[512];
    int tid = threadIdx.x;
    int v = (tid < nb) ? bsum[tid] : 0;
    s[tid] = v; __syncthreads();
    for (int off = 1; off < 512; off <<= 1) {
        int t = (tid >= off) ? s[tid - off] : 0; __syncthreads();
        s[tid] += t; __syncthreads();
    }
    if (tid < nb) bsum[tid] = s[tid] - v;      // exclusive
}

__global__ void scan3_kernel(int* __restrict__ rowptr, const int* __restrict__ bsum) {
    int i = blockIdx.x * 256 + threadIdx.x;
    if (i < N_NODES) rowptr[i] += bsum[blockIdx.x];
    if (i == 0) rowptr[N_NODES] = N_EDGES;
}

__global__ void scatter_kernel(const int* __restrict__ ei, const float* __restrict__ ew,
                               const int* __restrict__ rowptr, int* __restrict__ cnt,
                               int* __restrict__ ssrc, float* __restrict__ swt) {
    int e = blockIdx.x * blockDim.x + threadIdx.x;
    if (e >= N_EDGES) return;
    int dst = ei[N_EDGES + e];
    int pos = rowptr[dst] + atomicAdd(&cnt[dst], 1);
    ssrc[pos] = ei[e];
    swt[pos] = ew[e];
}

// ---------------- misc precompute ----------------
__global__ void bnprep_kernel(const float* __restrict__ v1, const float* __restrict__ v2,
                              const float* __restrict__ v3, float* __restrict__ rs) {
    int t = threadIdx.x;
    if (t < 128) rs[t] = 1.0f / sqrtf(v1[t] + BN_EPS);
    if (t < 64)  rs[128 + t] = 1.0f / sqrtf(v2[t] + BN_EPS);
    if (t < 32)  rs[192 + t] = 1.0f / sqrtf(v3[t] + BN_EPS);
}

__global__ void starts_kernel(const int* __restrict__ batch, int* __restrict__ starts) {
    int i = blockIdx.x * 256 + threadIdx.x;
    if (i >= N_NODES) return;
    int b = batch[i];
    int bp = (i == 0) ? -1 : batch[i - 1];
    for (int g = bp + 1; g <= b; ++g) starts[g] = i;
    if (i == N_NODES - 1)
        for (int g = b + 1; g <= N_GRAPHS; ++g) starts[g] = N_NODES;
}

// pad x [N,29] -> xp [N,32] (zeros in 29..31)
__global__ __launch_bounds__(256) void pad_x_kernel(const float* __restrict__ x,
                                                    float* __restrict__ xp) {
    int i = blockIdx.x * 256 + threadIdx.x;
    if (i >= N_NODES * 32) return;
    int n = i >> 5, c = i & 31;
    xp[i] = (c < 29) ? x[n * 29 + c] : 0.f;
}

// ---------------- layer-1 gather on padded x: agg[N,32] ----------------
__global__ __launch_bounds__(256) void agg_x_kernel(const float* __restrict__ xp,
        const int* __restrict__ rowptr, const int* __restrict__ ssrc,
        const float* __restrict__ swt, float* __restrict__ agg) {
    int tid = threadIdx.x;
    int node = blockIdx.x * 32 + (tid >> 3);
    int c = (tid & 7) * 4;
    int e0 = rowptr[node], e1 = rowptr[node + 1];
    float4 acc = {0.f, 0.f, 0.f, 0.f};
    int e = e0;
    // align e to 4 (order-preserving)
    for (; e < e1 && (e & 3); ++e) {
        int s0 = ssrc[e]; float w0 = swt[e];
        float4 y0 = *(const float4*)&xp[(size_t)s0 * 32 + c];
        acc.x = fmaf(w0, y0.x, acc.x); acc.y = fmaf(w0, y0.y, acc.y);
        acc.z = fmaf(w0, y0.z, acc.z); acc.w = fmaf(w0, y0.w, acc.w);
    }
    for (; e + 4 <= e1; e += 4) {
        int4   s4 = *(const int4*)&ssrc[e];
        float4 w4 = *(const float4*)&swt[e];
        float4 y0 = *(const float4*)&xp[(size_t)s4.x * 32 + c];
        float4 y1 = *(const float4*)&xp[(size_t)s4.y * 32 + c];
        float4 y2 = *(const float4*)&xp[(size_t)s4.z * 32 + c];
        float4 y3 = *(const float4*)&xp[(size_t)s4.w * 32 + c];
        acc.x = fmaf(w4.x, y0.x, acc.x); acc.y = fmaf(w4.x, y0.y, acc.y);
        acc.z = fmaf(w4.x, y0.z, acc.z); acc.w = fmaf(w4.x, y0.w, acc.w);
        acc.x = fmaf(w4.y, y1.x, acc.x); acc.y = fmaf(w4.y, y1.y, acc.y);
        acc.z = fmaf(w4.y, y1.z, acc.z); acc.w = fmaf(w4.y, y1.w, acc.w);
        acc.x = fmaf(w4.z, y2.x, acc.x); acc.y = fmaf(w4.z, y2.y, acc.y);
        acc.z = fmaf(w4.z, y2.z, acc.z); acc.w = fmaf(w4.z, y2.w, acc.w);
        acc.x = fmaf(w4.w, y3.x, acc.x); acc.y = fmaf(w4.w, y3.y, acc.y);
        acc.z = fmaf(w4.w, y3.z, acc.z); acc.w = fmaf(w4.w, y3.w, acc.w);
    }
    for (; e < e1; ++e) {
        int s0 = ssrc[e]; float w0 = swt[e];
        float4 y0 = *(const float4*)&xp[(size_t)s0 * 32 + c];
        acc.x = fmaf(w0, y0.x, acc.x); acc.y = fmaf(w0, y0.y, acc.y);
        acc.z = fmaf(w0, y0.z, acc.z); acc.w = fmaf(w0, y0.w, acc.w);
    }
    *(float4*)&agg[(size_t)node * 32 + c] = acc;
}

// h1 = relu(agg @ w1_rel + b1 + x @ w1_root), [N,256]; agg/xp padded stride 32.
__global__ __launch_bounds__(256) void dense1_kernel(const float* __restrict__ agg,
        const float* __restrict__ xp, const float* __restrict__ wrel,
        const float* __restrict__ wroot, const float* __restrict__ bias,
        float* __restrict__ out) {
    __shared__ float sA[32 * 32];
    __shared__ float sX[32 * 32];
    int tid = threadIdx.x;
    int node0 = blockIdx.x * 32;
    ((float4*)sA)[tid] = ((const float4*)(agg + (size_t)node0 * 32))[tid];
    ((float4*)sX)[tid] = ((const float4*)(xp + (size_t)node0 * 32))[tid];
    __syncthreads();
    int ct = tid & 63;      // 64 col-tiles of 4
    int mg = tid >> 6;      // 4 m-groups of 8 rows
    int c0 = ct * 4;
    float acc[8][4];
#pragma unroll
    for (int m = 0; m < 8; m++)
#pragma unroll
        for (int j = 0; j < 4; j++) acc[m][j] = 0.f;
    for (int k0 = 0; k0 < 28; k0 += 4) {
        float4 wr[4], wo[4];
#pragma unroll
        for (int j = 0; j < 4; j++) {
            wr[j] = *(const float4*)&wrel[(k0 + j) * 256 + c0];
            wo[j] = *(const float4*)&wroot[(k0 + j) * 256 + c0];
        }
#pragma unroll
        for (int m = 0; m < 8; m++) {
            float4 av = *(const float4*)&sA[(mg * 8 + m) * 32 + k0];
            float4 xv = *(const float4*)&sX[(mg * 8 + m) * 32 + k0];
            float as[4] = {av.x, av.y, av.z, av.w};
            float xs[4] = {xv.x, xv.y, xv.z, xv.w};
#pragma unroll
            for (int j = 0; j < 4; j++) {
                acc[m][0] = fmaf(as[j], wr[j].x, fmaf(xs[j], wo[j].x, acc[m][0]));
                acc[m][1] = fmaf(as[j], wr[j].y, fmaf(xs[j], wo[j].y, acc[m][1]));
                acc[m][2] = fmaf(as[j], wr[j].z, fmaf(xs[j], wo[j].z, acc[m][2]));
                acc[m][3] = fmaf(as[j], wr[j].w, fmaf(xs[j], wo[j].w, acc[m][3]));
            }
        }
    }
    {   // tail k = 28
        float4 wr = *(const float4*)&wrel[28 * 256 + c0];
        float4 wo = *(const float4*)&wroot[28 * 256 + c0];
#pragma unroll
        for (int m = 0; m < 8; m++) {
            float sa = sA[(mg * 8 + m) * 32 + 28];
            float sx = sX[(mg * 8 + m) * 32 + 28];
            acc[m][0] = fmaf(sa, wr.x, fmaf(sx, wo.x, acc[m][0]));
            acc[m][1] = fmaf(sa, wr.y, fmaf(sx, wo.y, acc[m][1]));
            acc[m][2] = fmaf(sa, wr.z, fmaf(sx, wo.z, acc[m][2]));
            acc[m][3] = fmaf(sa, wr.w, fmaf(sx, wo.w, acc[m][3]));
        }
    }
    float4 b4 = *(const float4*)&bias[c0];
#pragma unroll
    for (int m = 0; m < 8; m++) {
        int row = node0 + mg * 8 + m;
        float4 o;
        o.x = fmaxf(acc[m][0] + b4.x, 0.f);
        o.y = fmaxf(acc[m][1] + b4.y, 0.f);
        o.z = fmaxf(acc[m][2] + b4.z, 0.f);
        o.w = fmaxf(acc[m][3] + b4.w, 0.f);
        *(float4*)&out[(size_t)row * 256 + c0] = o;
    }
}

// ---------------- dual GEMM: y = in@wA, r = in@wB  ([N,K] @ [K,F]) ----------------
// R6 post-mortem: register double-buffers blew VGPR (148, occ 10%) — reverted
// to the R4 shape (RPM rows x 4 cols, VGPR ~52). R4's real bottleneck: all 4
// waves of a block load IDENTICAL W addresses every k0-step (cc spans all 2F
// cols within one wave) -> 4x redundant W stream + per-step L2 latency in
// lockstep. Fix: stage the W chunk in LDS too (one coalesced bulk load per
// block per chunk); inner loop reads W via contiguous conflict-free
// ds_read_b128. A-fragment reads stay wave-uniform broadcasts. FMA order per
// output unchanged -> bit-exact.
template <int K, int F, int RPM, int KC>
__global__ __launch_bounds__(256) void gemm_dual_kernel(const float* __restrict__ in,
        const float* __restrict__ wA, const float* __restrict__ wB,
        float* __restrict__ outA, float* __restrict__ outB) {
    constexpr int NT = 256;
    constexpr int NCT = F / 2;        // col-groups of 4 over 2F output cols
    constexpr int MG = NT / NCT;
    constexpr int ROWS = MG * RPM;
    constexpr int KC4 = KC / 4;
    constexpr int TF = 2 * F;
    constexpr int TF4 = TF / 4;
    __shared__ float sA[ROWS * KC];
    __shared__ float sW[KC * TF];
    int tid = threadIdx.x;
    size_t node0 = (size_t)blockIdx.x * ROWS;
    int ct = tid % NCT;
    int mg = tid / NCT;
    int c0 = ct * 4;                  // in [0, 2F)
    float* OUT;
    int cc;
    if (c0 < F) { OUT = outA; cc = c0; }
    else        { OUT = outB; cc = c0 - F; }
    float acc[RPM][4];
#pragma unroll
    for (int m = 0; m < RPM; m++)
#pragma unroll
        for (int j = 0; j < 4; j++) acc[m][j] = 0.f;
    const float* srow = sA + (size_t)(mg * RPM) * KC;
#pragma unroll 1
    for (int kb = 0; kb < K; kb += KC) {
        __syncthreads();
        // stage A chunk: rows [node0, node0+ROWS), cols [kb, kb+KC)
#pragma unroll
        for (int idx = tid; idx < ROWS * KC4; idx += NT) {
            int rr = idx / KC4, c4 = idx % KC4;
            *(float4*)&sA[rr * KC + c4 * 4] =
                *(const float4*)&in[(node0 + rr) * K + kb + c4 * 4];
        }
        // stage W chunk: rows [kb, kb+KC) of [wA | wB] -> sW[KC][2F]
#pragma unroll
        for (int idx = tid; idx < KC * TF4; idx += NT) {
            int rr = idx / TF4, cq = idx % TF4;
            int c = cq * 4;
            float4 wv = (c < F)
                ? *(const float4*)&wA[(size_t)(kb + rr) * F + c]
                : *(const float4*)&wB[(size_t)(kb + rr) * F + (c - F)];
            *(float4*)&sW[rr * TF + c] = wv;
        }
        __syncthreads();
#pragma unroll
        for (int k0 = 0; k0 < KC; k0 += 4) {
            float4 w0 = *(const float4*)&sW[(k0 + 0) * TF + c0];
            float4 w1 = *(const float4*)&sW[(k0 + 1) * TF + c0];
            float4 w2 = *(const float4*)&sW[(k0 + 2) * TF + c0];
            float4 w3 = *(const float4*)&sW[(k0 + 3) * TF + c0];
#pragma unroll
            for (int m = 0; m < RPM; m++) {
                float4 sm = *(const float4*)&srow[m * KC + k0];
                acc[m][0] = fmaf(sm.x, w0.x, acc[m][0]);
                acc[m][1] = fmaf(sm.x, w0.y, acc[m][1]);
                acc[m][2] = fmaf(sm.x, w0.z, acc[m][2]);
                acc[m][3] = fmaf(sm.x, w0.w, acc[m][3]);
                acc[m][0] = fmaf(sm.y, w1.x, acc[m][0]);
                acc[m][1] = fmaf(sm.y, w1.y, acc[m][1]);
                acc[m][2] = fmaf(sm.y, w1.z, acc[m][2]);
                acc[m][3] = fmaf(sm.y, w1.w, acc[m][3]);
                acc[m][0] = fmaf(sm.z, w2.x, acc[m][0]);
                acc[m][1] = fmaf(sm.z, w2.y, acc[m][1]);
                acc[m][2] = fmaf(sm.z, w2.z, acc[m][2]);
                acc[m][3] = fmaf(sm.z, w2.w, acc[m][3]);
                acc[m][0] = fmaf(sm.w, w3.x, acc[m][0]);
                acc[m][1] = fmaf(sm.w, w3.y, acc[m][1]);
                acc[m][2] = fmaf(sm.w, w3.z, acc[m][2]);
                acc[m][3] = fmaf(sm.w, w3.w, acc[m][3]);
            }
        }
    }
#pragma unroll
    for (int m = 0; m < RPM; m++) {
        size_t row = node0 + mg * RPM + m;
        float4 o = {acc[m][0], acc[m][1], acc[m][2], acc[m][3]};
        *(float4*)&OUT[row * F + cc] = o;
    }
}

// ---------------- combine: h = relu(bn(gather(y) + b + r)) ----------------
template <int F>
__global__ __launch_bounds__(256) void combine_kernel(const float* __restrict__ y,
        const float* __restrict__ r, const int* __restrict__ rowptr,
        const int* __restrict__ ssrc, const float* __restrict__ swt,
        const float* __restrict__ bias, const float* __restrict__ bg,
        const float* __restrict__ bb, const float* __restrict__ bm,
        const float* __restrict__ rs, float* __restrict__ h) {
    constexpr int TPN = F / 4;
    int tid = threadIdx.x;
    int node = blockIdx.x * (256 / TPN) + tid / TPN;
    int c = (tid % TPN) * 4;
    int e0 = rowptr[node], e1 = rowptr[node + 1];
    float4 acc = {0.f, 0.f, 0.f, 0.f};
    int e = e0;
    for (; e < e1 && (e & 3); ++e) {
        int s0 = ssrc[e]; float w0 = swt[e];
        float4 y0 = *(const float4*)&y[(size_t)s0 * F + c];
        acc.x = fmaf(w0, y0.x, acc.x); acc.y = fmaf(w0, y0.y, acc.y);
        acc.z = fmaf(w0, y0.z, acc.z); acc.w = fmaf(w0, y0.w, acc.w);
    }
    for (; e + 4 <= e1; e += 4) {
        int4   s4 = *(const int4*)&ssrc[e];
        float4 w4 = *(const float4*)&swt[e];
        float4 y0 = *(const float4*)&y[(size_t)s4.x * F + c];
        float4 y1 = *(const float4*)&y[(size_t)s4.y * F + c];
        float4 y2 = *(const float4*)&y[(size_t)s4.z * F + c];
        float4 y3 = *(const float4*)&y[(size_t)s4.w * F + c];
        acc.x = fmaf(w4.x, y0.x, acc.x); acc.y = fmaf(w4.x, y0.y, acc.y);
        acc.z = fmaf(w4.x, y0.z, acc.z); acc.w = fmaf(w4.x, y0.w, acc.w);
        acc.x = fmaf(w4.y, y1.x, acc.x); acc.y = fmaf(w4.y, y1.y, acc.y);
        acc.z = fmaf(w4.y, y1.z, acc.z); acc.w = fmaf(w4.y, y1.w, acc.w);
        acc.x = fmaf(w4.z, y2.x, acc.x); acc.y = fmaf(w4.z, y2.y, acc.y);
        acc.z = fmaf(w4.z, y2.z, acc.z); acc.w = fmaf(w4.z, y2.w, acc.w);
        acc.x = fmaf(w4.w, y3.x, acc.x); acc.y = fmaf(w4.w, y3.y, acc.y);
        acc.z = fmaf(w4.w, y3.z, acc.z); acc.w = fmaf(w4.w, y3.w, acc.w);
    }
    for (; e < e1; ++e) {
        int s0 = ssrc[e]; float w0 = swt[e];
        float4 y0 = *(const float4*)&y[(size_t)s0 * F + c];
        acc.x = fmaf(w0, y0.x, acc.x); acc.y = fmaf(w0, y0.y, acc.y);
        acc.z = fmaf(w0, y0.z, acc.z); acc.w = fmaf(w0, y0.w, acc.w);
    }
    float4 bi = *(const float4*)&bias[c];
    float4 rv = *(const float4*)&r[(size_t)node * F + c];
    float4 mu = *(const float4*)&bm[c];
    float4 rq = *(const float4*)&rs[c];
    float4 gm = *(const float4*)&bg[c];
    float4 bt = *(const float4*)&bb[c];
    float4 o;
    o.x = fmaxf((acc.x + bi.x + rv.x - mu.x) * rq.x * gm.x + bt.x, 0.f);
    o.y = fmaxf((acc.y + bi.y + rv.y - mu.y) * rq.y * gm.y + bt.y, 0.f);
    o.z = fmaxf((acc.z + bi.z + rv.z - mu.z) * rq.z * gm.z + bt.z, 0.f);
    o.w = fmaxf((acc.w + bi.w + rv.w - mu.w) * rq.w * gm.w + bt.w, 0.f);
    *(float4*)&h[(size_t)node * F + c] = o;
}

// ---------------- pool + fc + sigmoid ----------------
__global__ __launch_bounds__(256) void pool_fc_kernel(const float* __restrict__ h4,
        const int* __restrict__ starts, const float* __restrict__ fcw,
        const float* __restrict__ fcb, float* __restrict__ out) {
    int g = blockIdx.x;
    int tid = threadIdx.x;
    int i0 = starts[g], i1 = starts[g + 1];
    int ch = tid & 31, part = tid >> 5;
    float sum = 0.f;
    for (int i = i0 + part; i < i1; i += 8) sum += h4[(size_t)i * 32 + ch];
    __shared__ float sm[8][32];
    sm[part][ch] = sum;
    __syncthreads();
    if (tid < 32) {
        float tot = 0.f;
        for (int p = 0; p < 8; p++) tot += sm[p][tid];
        float cnt = (float)(i1 - i0);
        float mean = tot / fmaxf(cnt, 1.0f);
        sm[0][tid] = mean * fcw[tid];
    }
    __syncthreads();
    if (tid == 0) {
        float z = 0.f;
        for (int c = 0; c < 32; c++) z += sm[0][c];
        z += fcb[0];
        out[g] = 1.0f / (1.0f + expf(-z));
    }
}

extern "C" void kernel_launch(void* const* d_in, const int* in_sizes, int n_in,
                              void* d_out, int out_size, void* d_ws, size_t ws_size,
                              hipStream_t stream) {
    (void)in_sizes; (void)n_in; (void)out_size; (void)ws_size;
    const float* x       = (const float*)d_in[0];
    const int*   ei      = (const int*)d_in[1];
    const float* ew      = (const float*)d_in[2];
    const int*   batch   = (const int*)d_in[3];
    const float* w1_rel  = (const float*)d_in[4];
    const float* b1      = (const float*)d_in[5];
    const float* w1_root = (const float*)d_in[6];
    const float* w2_rel  = (const float*)d_in[7];
    const float* b2      = (const float*)d_in[8];
    const float* w2_root = (const float*)d_in[9];
    const float* w3_rel  = (const float*)d_in[10];
    const float* b3      = (const float*)d_in[11];
    const float* w3_root = (const float*)d_in[12];
    const float* w4_rel  = (const float*)d_in[13];
    const float* b4      = (const float*)d_in[14];
    const float* w4_root = (const float*)d_in[15];
    const float* bn1_g = (const float*)d_in[16];
    const float* bn1_b = (const float*)d_in[17];
    const float* bn1_m = (const float*)d_in[18];
    const float* bn2_g = (const float*)d_in[20];
    const float* bn2_b = (const float*)d_in[21];
    const float* bn2_m = (const float*)d_in[22];
    const float* bn3_g = (const float*)d_in[24];
    const float* bn3_b = (const float*)d_in[25];
    const float* bn3_m = (const float*)d_in[26];
    const float* fc_w = (const float*)d_in[28];
    const float* fc_b = (const float*)d_in[29];

    char* ws = (char*)d_ws;
    int*   rowptr = (int*)(ws + 0);                              // (N+1)*4
    int*   cnt    = (int*)(ws + (1ull << 20));                   // N*4
    int*   bsum   = (int*)(ws + (2ull << 20));                   // 391*4
    float* rs     = (float*)(ws + (2ull << 20) + (64ull << 10)); // 224 floats
    int*   starts = (int*)(ws + (2ull << 20) + (128ull << 10));  // 257*4
    int*   ssrc   = (int*)(ws + (4ull << 20));                   // E*4 = 6.4MB
    float* swt    = (float*)(ws + (11ull << 20));                // E*4 = 6.4MB
    float* bufA   = (float*)(ws + (18ull << 20));                // 104MB: h1 / r3,h3
    float* bufB   = (float*)(ws + (122ull << 20));               // 52MB:  xp / y2 / y3 / y4
    float* bufC   = (float*)(ws + (174ull << 20));               // 52MB:  agg / r2,h2 / r4,h4
    float* xp   = bufB;   // [N,32] padded x; dead before gemm2 writes bufB
    float* agg1 = bufC;   // [N,32] padded agg; dead before gemm2 writes bufC

    // CSR build (reused by all 4 layers)
    hipMemsetAsync(cnt, 0, N_NODES * 4, stream);
    hist_kernel<<<6250, 256, 0, stream>>>(ei, cnt);
    scan1_kernel<<<391, 256, 0, stream>>>(cnt, rowptr, bsum);
    scan2_kernel<<<1, 512, 0, stream>>>(bsum, 391);
    scan3_kernel<<<391, 256, 0, stream>>>(rowptr, bsum);
    hipMemsetAsync(cnt, 0, N_NODES * 4, stream);
    scatter_kernel<<<6250, 256, 0, stream>>>(ei, ew, rowptr, cnt, ssrc, swt);
    bnprep_kernel<<<1, 128, 0, stream>>>((const float*)d_in[19], (const float*)d_in[23],
                                         (const float*)d_in[27], rs);
    starts_kernel<<<391, 256, 0, stream>>>(batch, starts);

    // layer 1 (29 -> 256), aggregate-first on padded x
    pad_x_kernel<<<12500, 256, 0, stream>>>(x, xp);
    agg_x_kernel<<<3125, 256, 0, stream>>>(xp, rowptr, ssrc, swt, agg1);
    dense1_kernel<<<3125, 256, 0, stream>>>(agg1, xp, w1_rel, w1_root, b1, bufA);

    // layer 2 (256 -> 128): ROWS=64, KC=32 -> LDS 8+32=40 KiB, 4 blocks/CU
    gemm_dual_kernel<256, 128, 16, 32><<<1563, 256, 0, stream>>>(bufA, w2_rel, w2_root, bufB, bufC);
    combine_kernel<128><<<12500, 256, 0, stream>>>(bufB, bufC, rowptr, ssrc, swt,
                                                   b2, bn1_g, bn1_b, bn1_m, rs, bufC);

    // layer 3 (128 -> 64): ROWS=64, KC=32 -> LDS 8+16=24 KiB, 6 blocks/CU
    gemm_dual_kernel<128, 64, 8, 32><<<1563, 256, 0, stream>>>(bufC, w3_rel, w3_root, bufB, bufA);
    combine_kernel<64><<<6250, 256, 0, stream>>>(bufB, bufA, rowptr, ssrc, swt,
                                                 b3, bn2_g, bn2_b, bn2_m, rs + 128, bufA);

    // layer 4 (64 -> 32): ROWS=64, KC=64 -> single chunk, LDS 16+16=32 KiB
    gemm_dual_kernel<64, 32, 4, 64><<<1563, 256, 0, stream>>>(bufA, w4_rel, w4_root, bufB, bufC);
    combine_kernel<32><<<3125, 256, 0, stream>>>(bufB, bufC, rowptr, ssrc, swt,
                                                 b4, bn3_g, bn3_b, bn3_m, rs + 192, bufC);

    // pool + fc + sigmoid
    pool_fc_kernel<<<N_GRAPHS, 256, 0, stream>>>(bufC, starts, fc_w, fc_b, (float*)d_out);
}

// Round 8
// 775.065 us; speedup vs baseline: 1.1091x; 1.0258x over previous
//
#include <hip/hip_runtime.h>
#include <math.h>

#define N_NODES 100000
#define N_EDGES 1600000
#define N_GRAPHS 256
#define BN_EPS 1e-5f

// ---------------- CSR build ----------------
__global__ void hist_kernel(const int* __restrict__ ei, int* __restrict__ deg) {
    int e = blockIdx.x * blockDim.x + threadIdx.x;
    if (e < N_EDGES) atomicAdd(&deg[ei[N_EDGES + e]], 1);
}

__global__ void scan1_kernel(const int* __restrict__ deg, int* __restrict__ rowptr,
                             int* __restrict__ bsum) {
    __shared__ int s[256];
    int tid = threadIdx.x;
    int i = blockIdx.x * 256 + tid;
    int v = (i < N_NODES) ? deg[i] : 0;
    s[tid] = v; __syncthreads();
    for (int off = 1; off < 256; off <<= 1) {
        int t = (tid >= off) ? s[tid - off] : 0; __syncthreads();
        s[tid] += t; __syncthreads();
    }
    if (i < N_NODES) rowptr[i] = s[tid] - v;   // exclusive
    if (tid == 255) bsum[blockIdx.x] = s[255];
}

__global__ void scan2_kernel(int* bsum, int nb) {
    __shared__ int s[512];
    int tid = threadIdx.x;
    int v = (tid < nb) ? bsum[tid] : 0;
    s[tid] = v; __syncthreads();
    for (int off = 1; off < 512; off <<= 1) {
        int t = (tid >= off) ? s[tid - off] : 0; __syncthreads();
        s[tid] += t; __syncthreads();
    }
    if (tid < nb) bsum[tid] = s[tid] - v;      // exclusive
}

__global__ void scan3_kernel(int* __restrict__ rowptr, const int* __restrict__ bsum) {
    int i = blockIdx.x * 256 + threadIdx.x;
    if (i < N_NODES) rowptr[i] += bsum[blockIdx.x];
    if (i == 0) rowptr[N_NODES] = N_EDGES;
}

__global__ void scatter_kernel(const int* __restrict__ ei, const float* __restrict__ ew,
                               const int* __restrict__ rowptr, int* __restrict__ cnt,
                               int* __restrict__ ssrc, float* __restrict__ swt) {
    int e = blockIdx.x * blockDim.x + threadIdx.x;
    if (e >= N_EDGES) return;
    int dst = ei[N_EDGES + e];
    int pos = rowptr[dst] + atomicAdd(&cnt[dst], 1);
    ssrc[pos] = ei[e];
    swt[pos] = ew[e];
}

// ---------------- misc precompute ----------------
__global__ void bnprep_kernel(const float* __restrict__ v1, const float* __restrict__ v2,
                              const float* __restrict__ v3, float* __restrict__ rs) {
    int t = threadIdx.x;
    if (t < 128) rs[t] = 1.0f / sqrtf(v1[t] + BN_EPS);
    if (t < 64)  rs[128 + t] = 1.0f / sqrtf(v2[t] + BN_EPS);
    if (t < 32)  rs[192 + t] = 1.0f / sqrtf(v3[t] + BN_EPS);
}

__global__ void starts_kernel(const int* __restrict__ batch, int* __restrict__ starts) {
    int i = blockIdx.x * 256 + threadIdx.x;
    if (i >= N_NODES) return;
    int b = batch[i];
    int bp = (i == 0) ? -1 : batch[i - 1];
    for (int g = bp + 1; g <= b; ++g) starts[g] = i;
    if (i == N_NODES - 1)
        for (int g = b + 1; g <= N_GRAPHS; ++g) starts[g] = N_NODES;
}

// pad x [N,29] -> xp [N,32] (zeros in 29..31)
__global__ __launch_bounds__(256) void pad_x_kernel(const float* __restrict__ x,
                                                    float* __restrict__ xp) {
    int i = blockIdx.x * 256 + threadIdx.x;
    if (i >= N_NODES * 32) return;
    int n = i >> 5, c = i & 31;
    xp[i] = (c < 29) ? x[n * 29 + c] : 0.f;
}

// ---------------- layer-1 gather on padded x: agg[N,32] ----------------
__global__ __launch_bounds__(256) void agg_x_kernel(const float* __restrict__ xp,
        const int* __restrict__ rowptr, const int* __restrict__ ssrc,
        const float* __restrict__ swt, float* __restrict__ agg) {
    int tid = threadIdx.x;
    int node = blockIdx.x * 32 + (tid >> 3);
    int c = (tid & 7) * 4;
    int e0 = rowptr[node], e1 = rowptr[node + 1];
    float4 acc = {0.f, 0.f, 0.f, 0.f};
    int e = e0;
    // align e to 4 (order-preserving)
    for (; e < e1 && (e & 3); ++e) {
        int s0 = ssrc[e]; float w0 = swt[e];
        float4 y0 = *(const float4*)&xp[(size_t)s0 * 32 + c];
        acc.x = fmaf(w0, y0.x, acc.x); acc.y = fmaf(w0, y0.y, acc.y);
        acc.z = fmaf(w0, y0.z, acc.z); acc.w = fmaf(w0, y0.w, acc.w);
    }
    for (; e + 4 <= e1; e += 4) {
        int4   s4 = *(const int4*)&ssrc[e];
        float4 w4 = *(const float4*)&swt[e];
        float4 y0 = *(const float4*)&xp[(size_t)s4.x * 32 + c];
        float4 y1 = *(const float4*)&xp[(size_t)s4.y * 32 + c];
        float4 y2 = *(const float4*)&xp[(size_t)s4.z * 32 + c];
        float4 y3 = *(const float4*)&xp[(size_t)s4.w * 32 + c];
        acc.x = fmaf(w4.x, y0.x, acc.x); acc.y = fmaf(w4.x, y0.y, acc.y);
        acc.z = fmaf(w4.x, y0.z, acc.z); acc.w = fmaf(w4.x, y0.w, acc.w);
        acc.x = fmaf(w4.y, y1.x, acc.x); acc.y = fmaf(w4.y, y1.y, acc.y);
        acc.z = fmaf(w4.y, y1.z, acc.z); acc.w = fmaf(w4.y, y1.w, acc.w);
        acc.x = fmaf(w4.z, y2.x, acc.x); acc.y = fmaf(w4.z, y2.y, acc.y);
        acc.z = fmaf(w4.z, y2.z, acc.z); acc.w = fmaf(w4.z, y2.w, acc.w);
        acc.x = fmaf(w4.w, y3.x, acc.x); acc.y = fmaf(w4.w, y3.y, acc.y);
        acc.z = fmaf(w4.w, y3.z, acc.z); acc.w = fmaf(w4.w, y3.w, acc.w);
    }
    for (; e < e1; ++e) {
        int s0 = ssrc[e]; float w0 = swt[e];
        float4 y0 = *(const float4*)&xp[(size_t)s0 * 32 + c];
        acc.x = fmaf(w0, y0.x, acc.x); acc.y = fmaf(w0, y0.y, acc.y);
        acc.z = fmaf(w0, y0.z, acc.z); acc.w = fmaf(w0, y0.w, acc.w);
    }
    *(float4*)&agg[(size_t)node * 32 + c] = acc;
}

// h1 = relu(agg @ w1_rel + b1 + x @ w1_root), [N,256]; agg/xp padded stride 32.
__global__ __launch_bounds__(256) void dense1_kernel(const float* __restrict__ agg,
        const float* __restrict__ xp, const float* __restrict__ wrel,
        const float* __restrict__ wroot, const float* __restrict__ bias,
        float* __restrict__ out) {
    __shared__ float sA[32 * 32];
    __shared__ float sX[32 * 32];
    int tid = threadIdx.x;
    int node0 = blockIdx.x * 32;
    ((float4*)sA)[tid] = ((const float4*)(agg + (size_t)node0 * 32))[tid];
    ((float4*)sX)[tid] = ((const float4*)(xp + (size_t)node0 * 32))[tid];
    __syncthreads();
    int ct = tid & 63;      // 64 col-tiles of 4
    int mg = tid >> 6;      // 4 m-groups of 8 rows
    int c0 = ct * 4;
    float acc[8][4];
#pragma unroll
    for (int m = 0; m < 8; m++)
#pragma unroll
        for (int j = 0; j < 4; j++) acc[m][j] = 0.f;
    for (int k0 = 0; k0 < 28; k0 += 4) {
        float4 wr[4], wo[4];
#pragma unroll
        for (int j = 0; j < 4; j++) {
            wr[j] = *(const float4*)&wrel[(k0 + j) * 256 + c0];
            wo[j] = *(const float4*)&wroot[(k0 + j) * 256 + c0];
        }
#pragma unroll
        for (int m = 0; m < 8; m++) {
            float4 av = *(const float4*)&sA[(mg * 8 + m) * 32 + k0];
            float4 xv = *(const float4*)&sX[(mg * 8 + m) * 32 + k0];
            float as[4] = {av.x, av.y, av.z, av.w};
            float xs[4] = {xv.x, xv.y, xv.z, xv.w};
#pragma unroll
            for (int j = 0; j < 4; j++) {
                acc[m][0] = fmaf(as[j], wr[j].x, fmaf(xs[j], wo[j].x, acc[m][0]));
                acc[m][1] = fmaf(as[j], wr[j].y, fmaf(xs[j], wo[j].y, acc[m][1]));
                acc[m][2] = fmaf(as[j], wr[j].z, fmaf(xs[j], wo[j].z, acc[m][2]));
                acc[m][3] = fmaf(as[j], wr[j].w, fmaf(xs[j], wo[j].w, acc[m][3]));
            }
        }
    }
    {   // tail k = 28
        float4 wr = *(const float4*)&wrel[28 * 256 + c0];
        float4 wo = *(const float4*)&wroot[28 * 256 + c0];
#pragma unroll
        for (int m = 0; m < 8; m++) {
            float sa = sA[(mg * 8 + m) * 32 + 28];
            float sx = sX[(mg * 8 + m) * 32 + 28];
            acc[m][0] = fmaf(sa, wr.x, fmaf(sx, wo.x, acc[m][0]));
            acc[m][1] = fmaf(sa, wr.y, fmaf(sx, wo.y, acc[m][1]));
            acc[m][2] = fmaf(sa, wr.z, fmaf(sx, wo.z, acc[m][2]));
            acc[m][3] = fmaf(sa, wr.w, fmaf(sx, wo.w, acc[m][3]));
        }
    }
    float4 b4 = *(const float4*)&bias[c0];
#pragma unroll
    for (int m = 0; m < 8; m++) {
        int row = node0 + mg * 8 + m;
        float4 o;
        o.x = fmaxf(acc[m][0] + b4.x, 0.f);
        o.y = fmaxf(acc[m][1] + b4.y, 0.f);
        o.z = fmaxf(acc[m][2] + b4.z, 0.f);
        o.w = fmaxf(acc[m][3] + b4.w, 0.f);
        *(float4*)&out[(size_t)row * 256 + c0] = o;
    }
}

// ---------------- dual GEMM: y = in@wA, r = in@wB  ([N,K] @ [K,F]) ----------------
// Exact R4 structure (proven best: 52 VGPR, 16 KiB LDS, 197 us) with ONE change:
// for NCT==64 (gemm2) the lane mapping is remapped so a wave's 64 lanes cover
// only 16 col-groups (x4 duplicate) and 4 row-groups, instead of all 64
// col-groups. W-load transactions per wave drop 8 lines -> 2 lines (the
// coalescer dedups identical lane addresses), and waves cover disjoint column
// quarters (no cross-wave refetch). A-side LDS reads become 4-address; the
// +4-float mg-stride pad keeps them on distinct banks. FMA order per output
// unchanged -> bit-exact.
template <int K, int F, int RPM, int KC>
__global__ __launch_bounds__(256) void gemm_dual_kernel(const float* __restrict__ in,
        const float* __restrict__ wA, const float* __restrict__ wB,
        float* __restrict__ outA, float* __restrict__ outB) {
    constexpr int NT = 256;
    constexpr int NCT = F / 2;        // col-groups of 4 over 2F output cols
    constexpr int MG = NT / NCT;
    constexpr int ROWS = MG * RPM;
    constexpr int KC4 = KC / 4;
    constexpr int MSTRIDE = RPM * KC + 4;   // +4 floats: mg-groups on distinct banks
    __shared__ float s[MG * MSTRIDE];
    int tid = threadIdx.x;
    size_t node0 = (size_t)blockIdx.x * ROWS;
    int ct, mg;
    if constexpr (NCT == 64) {
        ct = (tid & 15) | ((tid >> 6) << 4);   // wave covers 16 col-groups (x4 dup)
        mg = (tid >> 4) & 3;                   // 4 row-groups within wave
    } else {
        ct = tid % NCT;
        mg = tid / NCT;
    }
    int c0 = ct * 4;
    const float* W;
    float* OUT;
    int cc;
    if (c0 < F) { W = wA; OUT = outA; cc = c0; }
    else        { W = wB; OUT = outB; cc = c0 - F; }
    float acc[RPM][4];
#pragma unroll
    for (int m = 0; m < RPM; m++)
#pragma unroll
        for (int j = 0; j < 4; j++) acc[m][j] = 0.f;
    const float* srow = s + (size_t)mg * MSTRIDE;
    for (int kb = 0; kb < K; kb += KC) {
        __syncthreads();
        // stage chunk: rows [node0, node0+ROWS), cols [kb, kb+KC)
        for (int idx = tid; idx < ROWS * KC4; idx += NT) {
            int rr = idx / KC4;
            int c4 = idx % KC4;
            *(float4*)&s[(rr / RPM) * MSTRIDE + (rr % RPM) * KC + c4 * 4] =
                *(const float4*)&in[(node0 + rr) * K + kb + c4 * 4];
        }
        __syncthreads();
        for (int k0 = 0; k0 < KC; k0 += 4) {
            float4 w0 = *(const float4*)&W[(kb + k0 + 0) * F + cc];
            float4 w1 = *(const float4*)&W[(kb + k0 + 1) * F + cc];
            float4 w2 = *(const float4*)&W[(kb + k0 + 2) * F + cc];
            float4 w3 = *(const float4*)&W[(kb + k0 + 3) * F + cc];
#pragma unroll
            for (int m = 0; m < RPM; m++) {
                float4 sm = *(const float4*)&srow[m * KC + k0];
                acc[m][0] = fmaf(sm.x, w0.x, acc[m][0]);
                acc[m][1] = fmaf(sm.x, w0.y, acc[m][1]);
                acc[m][2] = fmaf(sm.x, w0.z, acc[m][2]);
                acc[m][3] = fmaf(sm.x, w0.w, acc[m][3]);
                acc[m][0] = fmaf(sm.y, w1.x, acc[m][0]);
                acc[m][1] = fmaf(sm.y, w1.y, acc[m][1]);
                acc[m][2] = fmaf(sm.y, w1.z, acc[m][2]);
                acc[m][3] = fmaf(sm.y, w1.w, acc[m][3]);
                acc[m][0] = fmaf(sm.z, w2.x, acc[m][0]);
                acc[m][1] = fmaf(sm.z, w2.y, acc[m][1]);
                acc[m][2] = fmaf(sm.z, w2.z, acc[m][2]);
                acc[m][3] = fmaf(sm.z, w2.w, acc[m][3]);
                acc[m][0] = fmaf(sm.w, w3.x, acc[m][0]);
                acc[m][1] = fmaf(sm.w, w3.y, acc[m][1]);
                acc[m][2] = fmaf(sm.w, w3.z, acc[m][2]);
                acc[m][3] = fmaf(sm.w, w3.w, acc[m][3]);
            }
        }
    }
#pragma unroll
    for (int m = 0; m < RPM; m++) {
        size_t row = node0 + mg * RPM + m;
        float4 o = {acc[m][0], acc[m][1], acc[m][2], acc[m][3]};
        *(float4*)&OUT[row * F + cc] = o;
    }
}

// ---------------- combine: h = relu(bn(gather(y) + b + r)) ----------------
// thread owns 4 channels (float4); edge loop: alignment prologue, then x4
// unrolled with vectorized int4/float4 index+weight loads (order-preserving)
template <int F>
__global__ __launch_bounds__(256) void combine_kernel(const float* __restrict__ y,
        const float* __restrict__ r, const int* __restrict__ rowptr,
        const int* __restrict__ ssrc, const float* __restrict__ swt,
        const float* __restrict__ bias, const float* __restrict__ bg,
        const float* __restrict__ bb, const float* __restrict__ bm,
        const float* __restrict__ rs, float* __restrict__ h) {
    constexpr int TPN = F / 4;
    int tid = threadIdx.x;
    int node = blockIdx.x * (256 / TPN) + tid / TPN;
    int c = (tid % TPN) * 4;
    int e0 = rowptr[node], e1 = rowptr[node + 1];
    float4 acc = {0.f, 0.f, 0.f, 0.f};
    int e = e0;
    for (; e < e1 && (e & 3); ++e) {
        int s0 = ssrc[e]; float w0 = swt[e];
        float4 y0 = *(const float4*)&y[(size_t)s0 * F + c];
        acc.x = fmaf(w0, y0.x, acc.x); acc.y = fmaf(w0, y0.y, acc.y);
        acc.z = fmaf(w0, y0.z, acc.z); acc.w = fmaf(w0, y0.w, acc.w);
    }
    for (; e + 4 <= e1; e += 4) {
        int4   s4 = *(const int4*)&ssrc[e];
        float4 w4 = *(const float4*)&swt[e];
        float4 y0 = *(const float4*)&y[(size_t)s4.x * F + c];
        float4 y1 = *(const float4*)&y[(size_t)s4.y * F + c];
        float4 y2 = *(const float4*)&y[(size_t)s4.z * F + c];
        float4 y3 = *(const float4*)&y[(size_t)s4.w * F + c];
        acc.x = fmaf(w4.x, y0.x, acc.x); acc.y = fmaf(w4.x, y0.y, acc.y);
        acc.z = fmaf(w4.x, y0.z, acc.z); acc.w = fmaf(w4.x, y0.w, acc.w);
        acc.x = fmaf(w4.y, y1.x, acc.x); acc.y = fmaf(w4.y, y1.y, acc.y);
        acc.z = fmaf(w4.y, y1.z, acc.z); acc.w = fmaf(w4.y, y1.w, acc.w);
        acc.x = fmaf(w4.z, y2.x, acc.x); acc.y = fmaf(w4.z, y2.y, acc.y);
        acc.z = fmaf(w4.z, y2.z, acc.z); acc.w = fmaf(w4.z, y2.w, acc.w);
        acc.x = fmaf(w4.w, y3.x, acc.x); acc.y = fmaf(w4.w, y3.y, acc.y);
        acc.z = fmaf(w4.w, y3.z, acc.z); acc.w = fmaf(w4.w, y3.w, acc.w);
    }
    for (; e < e1; ++e) {
        int s0 = ssrc[e]; float w0 = swt[e];
        float4 y0 = *(const float4*)&y[(size_t)s0 * F + c];
        acc.x = fmaf(w0, y0.x, acc.x); acc.y = fmaf(w0, y0.y, acc.y);
        acc.z = fmaf(w0, y0.z, acc.z); acc.w = fmaf(w0, y0.w, acc.w);
    }
    float4 bi = *(const float4*)&bias[c];
    float4 rv = *(const float4*)&r[(size_t)node * F + c];
    float4 mu = *(const float4*)&bm[c];
    float4 rq = *(const float4*)&rs[c];
    float4 gm = *(const float4*)&bg[c];
    float4 bt = *(const float4*)&bb[c];
    float4 o;
    o.x = fmaxf((acc.x + bi.x + rv.x - mu.x) * rq.x * gm.x + bt.x, 0.f);
    o.y = fmaxf((acc.y + bi.y + rv.y - mu.y) * rq.y * gm.y + bt.y, 0.f);
    o.z = fmaxf((acc.z + bi.z + rv.z - mu.z) * rq.z * gm.z + bt.z, 0.f);
    o.w = fmaxf((acc.w + bi.w + rv.w - mu.w) * rq.w * gm.w + bt.w, 0.f);
    *(float4*)&h[(size_t)node * F + c] = o;
}

// ---------------- pool + fc + sigmoid ----------------
__global__ __launch_bounds__(256) void pool_fc_kernel(const float* __restrict__ h4,
        const int* __restrict__ starts, const float* __restrict__ fcw,
        const float* __restrict__ fcb, float* __restrict__ out) {
    int g = blockIdx.x;
    int tid = threadIdx.x;
    int i0 = starts[g], i1 = starts[g + 1];
    int ch = tid & 31, part = tid >> 5;
    float sum = 0.f;
    for (int i = i0 + part; i < i1; i += 8) sum += h4[(size_t)i * 32 + ch];
    __shared__ float sm[8][32];
    sm[part][ch] = sum;
    __syncthreads();
    if (tid < 32) {
        float tot = 0.f;
        for (int p = 0; p < 8; p++) tot += sm[p][tid];
        float cnt = (float)(i1 - i0);
        float mean = tot / fmaxf(cnt, 1.0f);
        sm[0][tid] = mean * fcw[tid];
    }
    __syncthreads();
    if (tid == 0) {
        float z = 0.f;
        for (int c = 0; c < 32; c++) z += sm[0][c];
        z += fcb[0];
        out[g] = 1.0f / (1.0f + expf(-z));
    }
}

extern "C" void kernel_launch(void* const* d_in, const int* in_sizes, int n_in,
                              void* d_out, int out_size, void* d_ws, size_t ws_size,
                              hipStream_t stream) {
    (void)in_sizes; (void)n_in; (void)out_size; (void)ws_size;
    const float* x       = (const float*)d_in[0];
    const int*   ei      = (const int*)d_in[1];
    const float* ew      = (const float*)d_in[2];
    const int*   batch   = (const int*)d_in[3];
    const float* w1_rel  = (const float*)d_in[4];
    const float* b1      = (const float*)d_in[5];
    const float* w1_root = (const float*)d_in[6];
    const float* w2_rel  = (const float*)d_in[7];
    const float* b2      = (const float*)d_in[8];
    const float* w2_root = (const float*)d_in[9];
    const float* w3_rel  = (const float*)d_in[10];
    const float* b3      = (const float*)d_in[11];
    const float* w3_root = (const float*)d_in[12];
    const float* w4_rel  = (const float*)d_in[13];
    const float* b4      = (const float*)d_in[14];
    const float* w4_root = (const float*)d_in[15];
    const float* bn1_g = (const float*)d_in[16];
    const float* bn1_b = (const float*)d_in[17];
    const float* bn1_m = (const float*)d_in[18];
    const float* bn2_g = (const float*)d_in[20];
    const float* bn2_b = (const float*)d_in[21];
    const float* bn2_m = (const float*)d_in[22];
    const float* bn3_g = (const float*)d_in[24];
    const float* bn3_b = (const float*)d_in[25];
    const float* bn3_m = (const float*)d_in[26];
    const float* fc_w = (const float*)d_in[28];
    const float* fc_b = (const float*)d_in[29];

    char* ws = (char*)d_ws;
    int*   rowptr = (int*)(ws + 0);                              // (N+1)*4
    int*   cnt    = (int*)(ws + (1ull << 20));                   // N*4
    int*   bsum   = (int*)(ws + (2ull << 20));                   // 391*4
    float* rs     = (float*)(ws + (2ull << 20) + (64ull << 10)); // 224 floats
    int*   starts = (int*)(ws + (2ull << 20) + (128ull << 10));  // 257*4
    int*   ssrc   = (int*)(ws + (4ull << 20));                   // E*4 = 6.4MB
    float* swt    = (float*)(ws + (11ull << 20));                // E*4 = 6.4MB
    float* bufA   = (float*)(ws + (18ull << 20));                // 104MB: h1 / r3,h3
    float* bufB   = (float*)(ws + (122ull << 20));               // 52MB:  xp / y2 / y3 / y4
    float* bufC   = (float*)(ws + (174ull << 20));               // 52MB:  agg / r2,h2 / r4,h4
    float* xp   = bufB;   // [N,32] padded x; dead before gemm2 writes bufB
    float* agg1 = bufC;   // [N,32] padded agg; dead before gemm2 writes bufC

    // CSR build (reused by all 4 layers)
    hipMemsetAsync(cnt, 0, N_NODES * 4, stream);
    hist_kernel<<<6250, 256, 0, stream>>>(ei, cnt);
    scan1_kernel<<<391, 256, 0, stream>>>(cnt, rowptr, bsum);
    scan2_kernel<<<1, 512, 0, stream>>>(bsum, 391);
    scan3_kernel<<<391, 256, 0, stream>>>(rowptr, bsum);
    hipMemsetAsync(cnt, 0, N_NODES * 4, stream);
    scatter_kernel<<<6250, 256, 0, stream>>>(ei, ew, rowptr, cnt, ssrc, swt);
    bnprep_kernel<<<1, 128, 0, stream>>>((const float*)d_in[19], (const float*)d_in[23],
                                         (const float*)d_in[27], rs);
    starts_kernel<<<391, 256, 0, stream>>>(batch, starts);

    // layer 1 (29 -> 256), aggregate-first on padded x
    pad_x_kernel<<<12500, 256, 0, stream>>>(x, xp);
    agg_x_kernel<<<3125, 256, 0, stream>>>(xp, rowptr, ssrc, swt, agg1);
    dense1_kernel<<<3125, 256, 0, stream>>>(agg1, xp, w1_rel, w1_root, b1, bufA);

    // layer 2 (256 -> 128): ROWS=64, KC=64 -> ~16 KiB LDS (remapped lanes)
    gemm_dual_kernel<256, 128, 16, 64><<<1563, 256, 0, stream>>>(bufA, w2_rel, w2_root, bufB, bufC);
    combine_kernel<128><<<12500, 256, 0, stream>>>(bufB, bufC, rowptr, ssrc, swt,
                                                   b2, bn1_g, bn1_b, bn1_m, rs, bufC);

    // layer 3 (128 -> 64): ROWS=64, KC=64 -> ~16 KiB LDS
    gemm_dual_kernel<128, 64, 8, 64><<<1563, 256, 0, stream>>>(bufC, w3_rel, w3_root, bufB, bufA);
    combine_kernel<64><<<6250, 256, 0, stream>>>(bufB, bufA, rowptr, ssrc, swt,
                                                 b3, bn2_g, bn2_b, bn2_m, rs + 128, bufA);

    // layer 4 (64 -> 32): ROWS=128, KC=32 -> ~16 KiB LDS
    gemm_dual_kernel<64, 32, 8, 32><<<782, 256, 0, stream>>>(bufA, w4_rel, w4_root, bufB, bufC);
    combine_kernel<32><<<3125, 256, 0, stream>>>(bufB, bufC, rowptr, ssrc, swt,
                                                 b4, bn3_g, bn3_b, bn3_m, rs + 192, bufC);

    // pool + fc + sigmoid
    pool_fc_kernel<<<N_GRAPHS, 256, 0, stream>>>(bufC, starts, fc_w, fc_b, (float*)d_out);
}